// Round 6
// baseline (578.830 us; speedup 1.0000x reference)
//
#include <hip/hip_runtime.h>
#include <hip/hip_bf16.h>

#define LN_EPS 1e-5f

typedef __attribute__((ext_vector_type(8))) short short8;   // 8 bf16
typedef __attribute__((ext_vector_type(4))) float f32x4;    // MFMA C/D frag

__device__ __forceinline__ ushort f2bf(float f) {
    __hip_bfloat16 h = __float2bfloat16(f);
    return *reinterpret_cast<ushort*>(&h);
}
__device__ __forceinline__ float bf2f(ushort u) {
    union { float f; unsigned int i; } c; c.i = ((unsigned int)u) << 16; return c.f;
}

// ---------------- init: slots0 = mu + exp(logsigma)*slots_init; zero LN0 sums --------
__global__ void kinit(const float* __restrict__ slots_init, const float* __restrict__ mu,
                      const float* __restrict__ logsig, float* __restrict__ slots,
                      float* __restrict__ sums) {
    int i = blockIdx.x * 256 + threadIdx.x;    // 262144 exactly
    int d = i & 255;
    slots[i] = mu[d] + __expf(logsig[d]) * slots_init[i];
    if (blockIdx.x == 0 && threadIdx.x < 128) sums[threadIdx.x] = 0.f;
}

// ---------------- weight prep --------------------------------------------------------
// blk 0-47   : qWc[e][d] = bf16 cast of qW (NO transpose; MFMA B-frag reads rows)
// blk 48-95  : kWT[d][e] = bf16 transpose of kW
// blk 96-191 : m1WT[d][j] = m1W[j][d]
// blk 192-287: m2WT[j][d] = m2W[d][j]
// blk 288-335: vWT[e][d]  = vW[d][e]
__global__ void ktrans(const float* __restrict__ qW, const float* __restrict__ kW,
                       const float* __restrict__ m1W, const float* __restrict__ m2W,
                       const float* __restrict__ vW,
                       ushort* __restrict__ qWc, ushort* __restrict__ kWT,
                       ushort* __restrict__ m1WT, ushort* __restrict__ m2WT,
                       ushort* __restrict__ vWT) {
    int blk = blockIdx.x, t = threadIdx.x;
    int col = t & 63, rq = t >> 6;
    if (blk < 48) {   // straight cast copy, 64x64 tile
        int it = blk >> 4, rem = blk & 15;
        int tr = rem >> 2, tc = rem & 3;
        const float* src = qW + it * 65536;
        ushort* dst = qWc + it * 65536;
        #pragma unroll
        for (int r = 0; r < 16; r++) {
            int row = r * 4 + rq;
            int idx = (tr * 64 + row) * 256 + tc * 64 + col;
            dst[idx] = f2bf(src[idx]);
        }
        return;
    }
    __shared__ float tile[64][65];
    const float* src; ushort* dst; int R, C, tr, tc;
    if (blk < 96) {
        int li = blk - 48; int it = li >> 4, rem = li & 15;
        R = 256; C = 256; tr = rem >> 2; tc = rem & 3;
        src = kW + it * 65536; dst = kWT + it * 65536;
    } else if (blk < 192) {
        int li = blk - 96; int it = li >> 5, rem = li & 31;
        R = 512; C = 256; tr = rem >> 2; tc = rem & 3;
        src = m1W + it * 131072; dst = m1WT + it * 131072;
    } else if (blk < 288) {
        int li = blk - 192; int it = li >> 5, rem = li & 31;
        R = 256; C = 512; tr = rem >> 3; tc = rem & 7;
        src = m2W + it * 131072; dst = m2WT + it * 131072;
    } else {
        int li = blk - 288; int it = li >> 4, rem = li & 15;
        R = 256; C = 256; tr = rem >> 2; tc = rem & 3;
        src = vW + it * 65536; dst = vWT + it * 65536;
    }
    #pragma unroll
    for (int r = 0; r < 16; r++) {
        int row = r * 4 + rq;
        tile[row][col] = src[(tr * 64 + row) * C + tc * 64 + col];
    }
    __syncthreads();
    #pragma unroll
    for (int r = 0; r < 16; r++) {
        int row = r * 4 + rq;
        dst[(tc * 64 + row) * R + tr * 64 + col] = f2bf(tile[col][row]);
    }
}

// ---------------- LN0 pass 1: per-batch sum/sumsq over N*DIN = 1M elems -------------
__global__ void l0a(const float* __restrict__ inp, float* __restrict__ sums) {
    int b = blockIdx.x >> 5, seg = blockIdx.x & 31;
    const float4* p = (const float4*)inp + (size_t)b * 262144 + seg * 8192 + threadIdx.x;
    float s = 0.f, sq = 0.f;
    #pragma unroll
    for (int k = 0; k < 32; k++) {
        float4 v = p[k * 256];
        s  += v.x + v.y + v.z + v.w;
        sq += v.x * v.x + v.y * v.y + v.z * v.z + v.w * v.w;
    }
    __shared__ float r1[256], r2[256];
    r1[threadIdx.x] = s; r2[threadIdx.x] = sq; __syncthreads();
    for (int st = 128; st > 0; st >>= 1) {
        if (threadIdx.x < st) { r1[threadIdx.x] += r1[threadIdx.x + st]; r2[threadIdx.x] += r2[threadIdx.x + st]; }
        __syncthreads();
    }
    if (threadIdx.x == 0) { atomicAdd(&sums[b], r1[0]); atomicAdd(&sums[64 + b], r2[0]); }
}

// ---------------- LN0 pass 2: normalize + write bf16 x in MFMA-frag order ------------
// xgs[tile16(16384)][ds(8)][lane(64)][j(8)]: x[tile16*16+(lane&15)][ds*32+(lane>>4)*8+j]
__global__ void l0bs(const float* __restrict__ inp, const float* __restrict__ ln0w,
                     const float* __restrict__ ln0b, const float* __restrict__ sums,
                     ushort* __restrict__ xgs) {
    int gw = blockIdx.x * 4 + (threadIdx.x >> 6);     // 4096 wave tasks
    int lane = threadIdx.x & 63, l15 = lane & 15, quad = lane >> 4;
    int ntile = gw >> 4;                              // 0..255 (within-batch 16-token tile)
    int ds = (gw >> 1) & 7;
    int b0 = (gw & 1) * 32;
    int n = ntile * 16 + l15;                         // within-batch token
    int dcol = ds * 32 + quad * 8;
    const float4* wp = (const float4*)(ln0w + n * 256 + dcol);
    const float4* bp = (const float4*)(ln0b + n * 256 + dcol);
    float4 w0 = wp[0], w1 = wp[1];
    float4 c0 = bp[0], c1 = bp[1];
    #pragma unroll 4
    for (int bi = 0; bi < 32; bi++) {
        int b = b0 + bi;
        float mean = sums[b] * (1.f / 1048576.f);
        float rstd = rsqrtf(sums[64 + b] * (1.f / 1048576.f) - mean * mean + LN_EPS);
        const float4* xp = (const float4*)(inp + (size_t)b * 1048576 + n * 256 + dcol);
        float4 v0 = xp[0], v1 = xp[1];
        ushort o[8];
        o[0] = f2bf((v0.x - mean) * rstd * w0.x + c0.x);
        o[1] = f2bf((v0.y - mean) * rstd * w0.y + c0.y);
        o[2] = f2bf((v0.z - mean) * rstd * w0.z + c0.z);
        o[3] = f2bf((v0.w - mean) * rstd * w0.w + c0.w);
        o[4] = f2bf((v1.x - mean) * rstd * w1.x + c1.x);
        o[5] = f2bf((v1.y - mean) * rstd * w1.y + c1.y);
        o[6] = f2bf((v1.z - mean) * rstd * w1.z + c1.z);
        o[7] = f2bf((v1.w - mean) * rstd * w1.w + c1.w);
        *(short8*)(xgs + ((size_t)((b * 256 + ntile) * 8 + ds) * 64 + lane) * 8) = *(short8*)o;
    }
}

// ---------------- per-iter: MFMA version of kq ---------------------------------------
// LN1(slots) -> q' = (sl@qW^T + qb)/16 -> qk = q'@kW, all via 16x16x32 MFMA.
__global__ void kqm(const float* __restrict__ slots, const float* __restrict__ ln1w,
                    const float* __restrict__ ln1b, const ushort* __restrict__ qWc,
                    const float* __restrict__ qb, const ushort* __restrict__ kWT,
                    const float* __restrict__ kb,
                    ushort* __restrict__ qkf, float* __restrict__ qkb,
                    float* __restrict__ denom) {
    int b = blockIdx.x, t = threadIdx.x;
    int lane = t & 63, w = t >> 6, l15 = lane & 15, quad = lane >> 4;
    __shared__ ushort slb[16 * 264];    // bf16 LN1'd slots [s][d], pitch 264 (16B rows)
    __shared__ ushort qsb[16 * 264];    // bf16 q'     [s][e]
    __shared__ ushort qkl[16 * 264];    // bf16 qk     [s][d]
    __shared__ float  qsf[16 * 260];    // f32  q' for qkb
    __shared__ float  r1[256], r2[256];

    // ---- LN1 ----
    const float* sp = slots + b * 4096;
    float vals[16]; float s = 0.f, sq = 0.f;
    #pragma unroll
    for (int k = 0; k < 16; k++) { float v = sp[k * 256 + t]; vals[k] = v; s += v; sq += v * v; }
    r1[t] = s; r2[t] = sq; __syncthreads();
    for (int st = 128; st > 0; st >>= 1) {
        if (t < st) { r1[t] += r1[t + st]; r2[t] += r2[t + st]; }
        __syncthreads();
    }
    float m  = r1[0] * (1.f / 4096.f);
    float rs = rsqrtf(r2[0] * (1.f / 4096.f) - m * m + LN_EPS);
    #pragma unroll
    for (int k = 0; k < 16; k++)
        slb[k * 264 + t] = f2bf((vals[k] - m) * rs * ln1w[k * 256 + t] + ln1b[k * 256 + t]);
    __syncthreads();

    // ---- pass1: q'[s,e] = (sum_d sl[s,d]*qW[e,d] + qb[e]) / 16 ----
    short8 af[8];
    #pragma unroll
    for (int ds = 0; ds < 8; ds++)
        af[ds] = *(const short8*)(&slb[l15 * 264 + ds * 32 + quad * 8]);
    #pragma unroll
    for (int p = 0; p < 4; p++) {
        int et = w * 4 + p;
        f32x4 c = f32x4{0.f, 0.f, 0.f, 0.f};
        #pragma unroll
        for (int ds = 0; ds < 8; ds++) {
            short8 bf_ = *(const short8*)(qWc + (size_t)(et * 16 + l15) * 256 + ds * 32 + quad * 8);
            c = __builtin_amdgcn_mfma_f32_16x16x32_bf16(af[ds], bf_, c, 0, 0, 0);
        }
        float qbv = qb[et * 16 + l15];
        #pragma unroll
        for (int r = 0; r < 4; r++) {
            float val = (c[r] + qbv) * (1.f / 16.f);
            qsf[(quad * 4 + r) * 260 + et * 16 + l15] = val;
            qsb[(quad * 4 + r) * 264 + et * 16 + l15] = f2bf(val);
        }
    }
    __syncthreads();

    // ---- qkb[s] = q'[s,:] . kb  (16 lanes per s, shfl reduce) ----
    {
        int ss = w * 4 + quad;          // s handled by this 16-lane group
        float pp = 0.f;
        #pragma unroll
        for (int e = 0; e < 16; e++) pp += qsf[ss * 260 + l15 * 16 + e] * kb[l15 * 16 + e];
        pp += __shfl_xor(pp, 1); pp += __shfl_xor(pp, 2);
        pp += __shfl_xor(pp, 4); pp += __shfl_xor(pp, 8);
        if (l15 == 0) qkb[b * 16 + ss] = pp;
    }
    if (t < 16) denom[b * 16 + t] = 0.f;

    // ---- pass2: qk[s,d] = sum_e q'[s,e]*kW[e,d]  (B from kWT[d][e]) ----
    short8 af2[8];
    #pragma unroll
    for (int es = 0; es < 8; es++)
        af2[es] = *(const short8*)(&qsb[l15 * 264 + es * 32 + quad * 8]);
    #pragma unroll
    for (int p = 0; p < 4; p++) {
        int dt = w * 4 + p;
        f32x4 c2 = f32x4{0.f, 0.f, 0.f, 0.f};
        #pragma unroll
        for (int es = 0; es < 8; es++) {
            short8 bf2 = *(const short8*)(kWT + (size_t)(dt * 16 + l15) * 256 + es * 32 + quad * 8);
            c2 = __builtin_amdgcn_mfma_f32_16x16x32_bf16(af2[es], bf2, c2, 0, 0, 0);
        }
        #pragma unroll
        for (int r = 0; r < 4; r++)
            qkl[(quad * 4 + r) * 264 + dt * 16 + l15] = f2bf(c2[r]);
    }
    __syncthreads();

    // ---- qkf: re-read qkl rows in A-frag order; wave w stores ds = w*2, w*2+1 ----
    #pragma unroll
    for (int i = 0; i < 2; i++) {
        int ds = w * 2 + i;
        short8 v = *(const short8*)(&qkl[l15 * 264 + ds * 32 + quad * 8]);
        *(short8*)(qkf + (size_t)(b * 8 + ds) * 512 + lane * 8) = v;
    }
}

// ---------------- THE hot kernel: dist = qk@x^T (+qkb) -> softmax -> ax = attn@x -----
// grid = B*16; 4 waves. dist consumes prefetch regs pf directly. ax B-frags come from
// xtT: x^T staged in EXACT ax-B-frag order via in-register MFMA-identity transpose
// (D = A*I is exact; bf16 truncate of bf16-representable values is exact).
// xtT element (frag = dtile*2+ns, lane L, j) = x[n=ns*32+(L>>4)*8+j][d=dtile*16+(L&15)]
// Writer (w,quad,l15) holds C-frag D[n=w*16+quad*4+r][d=ds*32+half*16+l15] ->
//   addr = (ds*2+half)*1024 + (w>>1)*512 + ((w*2+(quad>>1))&3)*128 + l15*8 + (quad&1)*4 + r
// (bijection verified element-wise).
__launch_bounds__(256, 4)
__global__ void katt(const ushort* __restrict__ xgs, const ushort* __restrict__ qkf,
                     const float* __restrict__ qkb, float* __restrict__ denom,
                     float* __restrict__ partials) {
    int b = blockIdx.x >> 4, chunk = blockIdx.x & 15;
    int tid = threadIdx.x;
    int lane = tid & 63, w = tid >> 6;
    int l15 = lane & 15, quad = lane >> 4;

    __shared__ ushort xtT[16384];       // x^T in ax-B-frag order (32 KB)
    __shared__ ushort attn[16 * 72];    // attn [s][n_local], pitch 72

    // identity B-frags for MFMA transpose: Ilo[k][c]=d(k,c), Ihi[k][c]=d(k,c+16)
    short8 ilo, ihi;
    #pragma unroll
    for (int j = 0; j < 8; j++) {
        ilo[j] = (short)((quad * 8 + j == l15)      ? 0x3F80 : 0);
        ihi[j] = (short)((quad * 8 + j == l15 + 16) ? 0x3F80 : 0);
    }
    int wbase = (w >> 1) * 512 + ((w * 2 + (quad >> 1)) & 3) * 128 + l15 * 8 + (quad & 1) * 4;

    short8 qkfr[8];
    #pragma unroll
    for (int ds = 0; ds < 8; ds++)
        qkfr[ds] = *(const short8*)(qkf + ((size_t)(b * 8 + ds) * 512 + lane * 8));
    float4 qo = *(const float4*)(qkb + b * 16 + quad * 4);

    f32x4 pacc[4];
    #pragma unroll
    for (int u = 0; u < 4; u++) pacc[u] = f32x4{0.f, 0.f, 0.f, 0.f};
    float dp0 = 0.f, dp1 = 0.f, dp2 = 0.f, dp3 = 0.f;

    int tile0 = b * 256 + chunk * 16;

    short8 pf[8];
    #pragma unroll
    for (int i = 0; i < 8; i++)
        pf[i] = *(const short8*)(xgs + (((size_t)(tile0 + w) * 8 + i) * 64 + lane) * 8);

    #pragma unroll 1
    for (int sub = 0; sub < 4; sub++) {
        __syncthreads();                // prior ax done reading xtT/attn
        // ===== dist from pf =====
        f32x4 dc = f32x4{0.f, 0.f, 0.f, 0.f};
        #pragma unroll
        for (int ds = 0; ds < 8; ds++)
            dc = __builtin_amdgcn_mfma_f32_16x16x32_bf16(qkfr[ds], pf[ds], dc, 0, 0, 0);
        dc[0] += qo.x; dc[1] += qo.y; dc[2] += qo.z; dc[3] += qo.w;
        float mx = fmaxf(fmaxf(dc[0], dc[1]), fmaxf(dc[2], dc[3]));
        mx = fmaxf(mx, __shfl_xor(mx, 16));
        mx = fmaxf(mx, __shfl_xor(mx, 32));
        float e0 = __expf(dc[0] - mx), e1 = __expf(dc[1] - mx);
        float e2 = __expf(dc[2] - mx), e3 = __expf(dc[3] - mx);
        float lsum = e0 + e1 + e2 + e3;
        lsum += __shfl_xor(lsum, 16); lsum += __shfl_xor(lsum, 32);
        float inv = 1.f / lsum;
        float p0 = e0 * inv, p1 = e1 * inv, p2 = e2 * inv, p3 = e3 * inv;
        dp0 += p0; dp1 += p1; dp2 += p2; dp3 += p3;
        attn[(quad * 4 + 0) * 72 + w * 16 + l15] = f2bf(p0);
        attn[(quad * 4 + 1) * 72 + w * 16 + l15] = f2bf(p1);
        attn[(quad * 4 + 2) * 72 + w * 16 + l15] = f2bf(p2);
        attn[(quad * 4 + 3) * 72 + w * 16 + l15] = f2bf(p3);
        // ===== transpose pf -> xtT (B-frag order) =====
        f32x4 zz = f32x4{0.f, 0.f, 0.f, 0.f};
        #pragma unroll
        for (int ds = 0; ds < 8; ds++) {
            f32x4 tlo = __builtin_amdgcn_mfma_f32_16x16x32_bf16(pf[ds], ilo, zz, 0, 0, 0);
            f32x4 thi = __builtin_amdgcn_mfma_f32_16x16x32_bf16(pf[ds], ihi, zz, 0, 0, 0);
            unsigned lo0 = (__float_as_uint(tlo[0]) >> 16) | (__float_as_uint(tlo[1]) & 0xFFFF0000u);
            unsigned lo1 = (__float_as_uint(tlo[2]) >> 16) | (__float_as_uint(tlo[3]) & 0xFFFF0000u);
            unsigned hi0 = (__float_as_uint(thi[0]) >> 16) | (__float_as_uint(thi[1]) & 0xFFFF0000u);
            unsigned hi1 = (__float_as_uint(thi[2]) >> 16) | (__float_as_uint(thi[3]) & 0xFFFF0000u);
            *(uint2*)(&xtT[(ds * 2 + 0) * 1024 + wbase]) = make_uint2(lo0, lo1);
            *(uint2*)(&xtT[(ds * 2 + 1) * 1024 + wbase]) = make_uint2(hi0, hi1);
        }
        if (sub < 3) {                  // pf dead after dist+transpose -> prefetch next
            #pragma unroll
            for (int i = 0; i < 8; i++)
                pf[i] = *(const short8*)(xgs + (((size_t)(tile0 + (sub + 1) * 4 + w) * 8 + i) * 64 + lane) * 8);
        }
        __syncthreads();                // xtT + attn visible to all waves

        // ===== ax: pacc[s][d] += sum_n attn[s,n]*x[n,d]; wave w owns d [w*64,(w+1)*64) =====
        #pragma unroll
        for (int ns = 0; ns < 2; ns++) {
            short8 aa = *(const short8*)(&attn[l15 * 72 + ns * 32 + quad * 8]);
            #pragma unroll
            for (int u = 0; u < 4; u++) {
                short8 bb = *(const short8*)(&xtT[((w * 4 + u) * 2 + ns) * 512 + lane * 8]);
                pacc[u] = __builtin_amdgcn_mfma_f32_16x16x32_bf16(aa, bb, pacc[u], 0, 0, 0);
            }
        }
    }

    #pragma unroll
    for (int m = 1; m < 16; m <<= 1) {
        dp0 += __shfl_xor(dp0, m); dp1 += __shfl_xor(dp1, m);
        dp2 += __shfl_xor(dp2, m); dp3 += __shfl_xor(dp3, m);
    }
    if (l15 == 0) {
        atomicAdd(&denom[b * 16 + quad * 4 + 0], dp0);
        atomicAdd(&denom[b * 16 + quad * 4 + 1], dp1);
        atomicAdd(&denom[b * 16 + quad * 4 + 2], dp2);
        atomicAdd(&denom[b * 16 + quad * 4 + 3], dp3);
    }

    float* pout = partials + (size_t)(b * 16 + chunk) * 4096;   // [s][d]
    #pragma unroll
    for (int u = 0; u < 4; u++)
        #pragma unroll
        for (int r = 0; r < 4; r++)
            pout[(quad * 4 + r) * 256 + (w * 4 + u) * 16 + l15] = pacc[u][r];
}

// ---------------- reduce chunks + apply vW^T + vb, divide by denom -------------------
__global__ void kred2(const float* __restrict__ partials, const float* __restrict__ denom,
                      const ushort* __restrict__ vWT, const float* __restrict__ vb,
                      float* __restrict__ slots) {
    int b = blockIdx.x >> 2, dq = blockIdx.x & 3, t = threadIdx.x;
    __shared__ float axs[4096];
    __shared__ float dn[16];
    #pragma unroll
    for (int i = 0; i < 16; i++) {
        int idx = i * 256 + t;
        float ssum = 0.f;
        #pragma unroll
        for (int c = 0; c < 16; c++) ssum += partials[(size_t)b * 65536 + c * 4096 + idx];
        axs[idx] = ssum;
    }
    if (t < 16) dn[t] = denom[b * 16 + t];
    __syncthreads();
    int d = dq * 64 + (t & 63), sg = t >> 6;
    float acc[4];
    #pragma unroll
    for (int i = 0; i < 4; i++) acc[i] = 0.f;
    for (int e = 0; e < 256; e++) {
        float wv = bf2f(vWT[e * 256 + d]);
        #pragma unroll
        for (int i = 0; i < 4; i++) acc[i] += axs[(sg + i * 4) * 256 + e] * wv;
    }
    float vbd = vb[d];
    #pragma unroll
    for (int i = 0; i < 4; i++) {
        int s = sg + i * 4;
        float A = dn[s];
        slots[b * 4096 + s * 256 + d] = (acc[i] + vbd * A) / (A + 1e-7f);
    }
}

// ---------------- LN2 + MLP layer 1 (relu) -> htmp bf16 ------------------------------
__global__ void kfin1(const float* __restrict__ slots_in, const float* __restrict__ ln2w,
                      const float* __restrict__ ln2b, const ushort* __restrict__ m1WT,
                      const float* __restrict__ m1b, ushort* __restrict__ htmp) {
    int b = blockIdx.x >> 2, hq = blockIdx.x & 3, t = threadIdx.x;
    __shared__ float s2[4096];
    __shared__ float r1[256], r2[256];
    const float* sp = slots_in + b * 4096;
    float vals[16]; float s = 0.f, sq = 0.f;
    #pragma unroll
    for (int k = 0; k < 16; k++) { float v = sp[k * 256 + t]; vals[k] = v; s += v; sq += v * v; }
    r1[t] = s; r2[t] = sq; __syncthreads();
    for (int st = 128; st > 0; st >>= 1) {
        if (t < st) { r1[t] += r1[t + st]; r2[t] += r2[t + st]; }
        __syncthreads();
    }
    float m  = r1[0] * (1.f / 4096.f);
    float rs = rsqrtf(r2[0] * (1.f / 4096.f) - m * m + LN_EPS);
    #pragma unroll
    for (int k = 0; k < 16; k++)
        s2[k * 256 + t] = (vals[k] - m) * rs * ln2w[k * 256 + t] + ln2b[k * 256 + t];
    __syncthreads();
    int j = hq * 128 + (t & 127), sg2 = t >> 7;
    float acc[8];
    #pragma unroll
    for (int i = 0; i < 8; i++) acc[i] = 0.f;
    for (int d = 0; d < 256; d++) {
        float wv = bf2f(m1WT[d * 512 + j]);
        #pragma unroll
        for (int i = 0; i < 8; i++) acc[i] += s2[(sg2 + i * 2) * 256 + d] * wv;
    }
    float bias = m1b[j];
    #pragma unroll
    for (int i = 0; i < 8; i++)
        htmp[b * 8192 + (sg2 + i * 2) * 512 + j] = f2bf(fmaxf(acc[i] + bias, 0.f));
}

// ---------------- MLP layer 2 + residual ---------------------------------------------
__global__ void kfin2(const ushort* __restrict__ htmp, const ushort* __restrict__ m2WT,
                      const float* __restrict__ m2b, float* __restrict__ slots,
                      float* __restrict__ final_out, int write_final) {
    int b = blockIdx.x >> 2, dq = blockIdx.x & 3, t = threadIdx.x;
    __shared__ float hl[8192];
    #pragma unroll
    for (int i = 0; i < 32; i++) {
        int idx = i * 256 + t;
        hl[idx] = bf2f(htmp[b * 8192 + idx]);
    }
    __syncthreads();
    int d = dq * 64 + (t & 63), sg = t >> 6;
    float acc[4];
    #pragma unroll
    for (int i = 0; i < 4; i++) acc[i] = 0.f;
    for (int j = 0; j < 512; j++) {
        float wv = bf2f(m2WT[j * 256 + d]);
        #pragma unroll
        for (int i = 0; i < 4; i++) acc[i] += hl[(sg + i * 4) * 512 + j] * wv;
    }
    float bias2 = m2b[d];
    #pragma unroll
    for (int i = 0; i < 4; i++) {
        int s = sg + i * 4;
        float raw = slots[b * 4096 + s * 256 + d];
        float val = raw + acc[i] + bias2;
        slots[b * 4096 + s * 256 + d] = val;
        if (write_final) final_out[b * 4096 + s * 256 + d] = val;
    }
}

extern "C" void kernel_launch(void* const* d_in, const int* in_sizes, int n_in,
                              void* d_out, int out_size, void* d_ws, size_t ws_size,
                              hipStream_t stream) {
    const float* inputs     = (const float*)d_in[0];
    const float* slots_init = (const float*)d_in[1];
    const float* mu         = (const float*)d_in[2];
    const float* logsig     = (const float*)d_in[3];
    const float* ln0w       = (const float*)d_in[4];
    const float* ln0b       = (const float*)d_in[5];
    const float* ln1w       = (const float*)d_in[6];
    const float* ln1b       = (const float*)d_in[7];
    const float* ln2w       = (const float*)d_in[8];
    const float* ln2b       = (const float*)d_in[9];
    const float* qW         = (const float*)d_in[10];
    const float* qb         = (const float*)d_in[11];
    const float* kW         = (const float*)d_in[12];
    const float* kb         = (const float*)d_in[13];
    const float* vW         = (const float*)d_in[14];
    const float* vb         = (const float*)d_in[15];
    const float* m1W        = (const float*)d_in[16];
    const float* m1b        = (const float*)d_in[17];
    const float* m2W        = (const float*)d_in[18];
    const float* m2b        = (const float*)d_in[19];

    char* ws = (char*)d_ws;
    ushort* xgs     = (ushort*)(ws);                   // 134,217,728 B
    float*  partials= (float*)(ws + 134217728);        //  16,777,216 B
    ushort* qkf     = (ushort*)(ws + 150994944);       //     524,288 B
    ushort* htmp    = (ushort*)(ws + 151519232);       //   1,048,576 B
    float*  slots   = (float*)(ws + 152567808);        //   1,048,576 B
    ushort* qWc     = (ushort*)(ws + 153616384);       //     393,216 B
    ushort* m1WT    = (ushort*)(ws + 154009600);       //     786,432 B
    ushort* m2WT    = (ushort*)(ws + 154796032);       //     786,432 B
    ushort* vWT     = (ushort*)(ws + 155582464);       //     393,216 B
    float*  denom   = (float*)(ws + 155975680);        //       4,096 B
    float*  qkb     = (float*)(ws + 155979776);        //       4,096 B
    float*  sums    = (float*)(ws + 155983872);        //         512 B (pad to 155,984,384)
    ushort* kWT     = (ushort*)(ws + 155984384);       //     393,216 B
    // total 156,377,600 B <= 157,295,104 B proven available

    kinit<<<1024, 256, 0, stream>>>(slots_init, mu, logsig, slots, sums);
    ktrans<<<336, 256, 0, stream>>>(qW, kW, m1W, m2W, vW, qWc, kWT, m1WT, m2WT, vWT);
    l0a<<<2048, 256, 0, stream>>>(inputs, sums);
    l0bs<<<1024, 256, 0, stream>>>(inputs, ln0w, ln0b, sums, xgs);

    for (int it = 0; it < 3; it++) {
        kqm<<<64, 256, 0, stream>>>(slots, ln1w, ln1b, qWc + it * 65536, qb + it * 256,
                                    kWT + it * 65536, kb + it * 256, qkf, qkb, denom);
        katt<<<1024, 256, 0, stream>>>(xgs, qkf, qkb, denom, partials);
        kred2<<<256, 256, 0, stream>>>(partials, denom, vWT + it * 65536, vb + it * 256, slots);
        kfin1<<<256, 256, 0, stream>>>(slots, ln2w, ln2b, m1WT + it * 131072, m1b + it * 512, htmp);
        kfin2<<<256, 256, 0, stream>>>(htmp, m2WT + it * 131072, m2b + it * 256, slots,
                                       (float*)d_out, it == 2 ? 1 : 0);
    }
}

// Round 7
// 578.677 us; speedup vs baseline: 1.0003x; 1.0003x over previous
//
#include <hip/hip_runtime.h>
#include <hip/hip_bf16.h>

#define LN_EPS 1e-5f

typedef __attribute__((ext_vector_type(8))) short short8;   // 8 bf16
typedef __attribute__((ext_vector_type(4))) float f32x4;    // MFMA C/D frag

__device__ __forceinline__ ushort f2bf(float f) {
    __hip_bfloat16 h = __float2bfloat16(f);
    return *reinterpret_cast<ushort*>(&h);
}
__device__ __forceinline__ float bf2f(ushort u) {
    union { float f; unsigned int i; } c; c.i = ((unsigned int)u) << 16; return c.f;
}

// ---------------- init: slots0 = mu + exp(logsigma)*slots_init; zero LN0 sums --------
__global__ void kinit(const float* __restrict__ slots_init, const float* __restrict__ mu,
                      const float* __restrict__ logsig, float* __restrict__ slots,
                      float* __restrict__ sums) {
    int i = blockIdx.x * 256 + threadIdx.x;    // 262144 exactly
    int d = i & 255;
    slots[i] = mu[d] + __expf(logsig[d]) * slots_init[i];
    if (blockIdx.x == 0 && threadIdx.x < 128) sums[threadIdx.x] = 0.f;
}

// ---------------- weight prep --------------------------------------------------------
// blk 0-47   : qWc[e][d] = bf16 cast of qW (NO transpose; MFMA B-frag reads rows)
// blk 48-95  : kWT[d][e] = bf16 transpose of kW
// blk 96-191 : m1WT[d][j] = m1W[j][d]
// blk 192-287: m2WT[j][d] = m2W[d][j]
// blk 288-335: vWT[e][d]  = vW[d][e]
__global__ void ktrans(const float* __restrict__ qW, const float* __restrict__ kW,
                       const float* __restrict__ m1W, const float* __restrict__ m2W,
                       const float* __restrict__ vW,
                       ushort* __restrict__ qWc, ushort* __restrict__ kWT,
                       ushort* __restrict__ m1WT, ushort* __restrict__ m2WT,
                       ushort* __restrict__ vWT) {
    int blk = blockIdx.x, t = threadIdx.x;
    int col = t & 63, rq = t >> 6;
    if (blk < 48) {   // straight cast copy, 64x64 tile
        int it = blk >> 4, rem = blk & 15;
        int tr = rem >> 2, tc = rem & 3;
        const float* src = qW + it * 65536;
        ushort* dst = qWc + it * 65536;
        #pragma unroll
        for (int r = 0; r < 16; r++) {
            int row = r * 4 + rq;
            int idx = (tr * 64 + row) * 256 + tc * 64 + col;
            dst[idx] = f2bf(src[idx]);
        }
        return;
    }
    __shared__ float tile[64][65];
    const float* src; ushort* dst; int R, C, tr, tc;
    if (blk < 96) {
        int li = blk - 48; int it = li >> 4, rem = li & 15;
        R = 256; C = 256; tr = rem >> 2; tc = rem & 3;
        src = kW + it * 65536; dst = kWT + it * 65536;
    } else if (blk < 192) {
        int li = blk - 96; int it = li >> 5, rem = li & 31;
        R = 512; C = 256; tr = rem >> 2; tc = rem & 3;
        src = m1W + it * 131072; dst = m1WT + it * 131072;
    } else if (blk < 288) {
        int li = blk - 192; int it = li >> 5, rem = li & 31;
        R = 256; C = 512; tr = rem >> 3; tc = rem & 7;
        src = m2W + it * 131072; dst = m2WT + it * 131072;
    } else {
        int li = blk - 288; int it = li >> 4, rem = li & 15;
        R = 256; C = 256; tr = rem >> 2; tc = rem & 3;
        src = vW + it * 65536; dst = vWT + it * 65536;
    }
    #pragma unroll
    for (int r = 0; r < 16; r++) {
        int row = r * 4 + rq;
        tile[row][col] = src[(tr * 64 + row) * C + tc * 64 + col];
    }
    __syncthreads();
    #pragma unroll
    for (int r = 0; r < 16; r++) {
        int row = r * 4 + rq;
        dst[(tc * 64 + row) * R + tr * 64 + col] = f2bf(tile[col][row]);
    }
}

// ---------------- LN0 pass 1: per-batch sum/sumsq over N*DIN = 1M elems -------------
__global__ void l0a(const float* __restrict__ inp, float* __restrict__ sums) {
    int b = blockIdx.x >> 5, seg = blockIdx.x & 31;
    const float4* p = (const float4*)inp + (size_t)b * 262144 + seg * 8192 + threadIdx.x;
    float s = 0.f, sq = 0.f;
    #pragma unroll
    for (int k = 0; k < 32; k++) {
        float4 v = p[k * 256];
        s  += v.x + v.y + v.z + v.w;
        sq += v.x * v.x + v.y * v.y + v.z * v.z + v.w * v.w;
    }
    __shared__ float r1[256], r2[256];
    r1[threadIdx.x] = s; r2[threadIdx.x] = sq; __syncthreads();
    for (int st = 128; st > 0; st >>= 1) {
        if (threadIdx.x < st) { r1[threadIdx.x] += r1[threadIdx.x + st]; r2[threadIdx.x] += r2[threadIdx.x + st]; }
        __syncthreads();
    }
    if (threadIdx.x == 0) { atomicAdd(&sums[b], r1[0]); atomicAdd(&sums[64 + b], r2[0]); }
}

// ---------------- LN0 pass 2: normalize + write bf16 x in MFMA-frag order ------------
// xgs[tile16(16384)][ds(8)][lane(64)][j(8)]: x[tile16*16+(lane&15)][ds*32+(lane>>4)*8+j]
__global__ void l0bs(const float* __restrict__ inp, const float* __restrict__ ln0w,
                     const float* __restrict__ ln0b, const float* __restrict__ sums,
                     ushort* __restrict__ xgs) {
    int gw = blockIdx.x * 4 + (threadIdx.x >> 6);     // 4096 wave tasks
    int lane = threadIdx.x & 63, l15 = lane & 15, quad = lane >> 4;
    int ntile = gw >> 4;                              // 0..255 (within-batch 16-token tile)
    int ds = (gw >> 1) & 7;
    int b0 = (gw & 1) * 32;
    int n = ntile * 16 + l15;                         // within-batch token
    int dcol = ds * 32 + quad * 8;
    const float4* wp = (const float4*)(ln0w + n * 256 + dcol);
    const float4* bp = (const float4*)(ln0b + n * 256 + dcol);
    float4 w0 = wp[0], w1 = wp[1];
    float4 c0 = bp[0], c1 = bp[1];
    #pragma unroll 4
    for (int bi = 0; bi < 32; bi++) {
        int b = b0 + bi;
        float mean = sums[b] * (1.f / 1048576.f);
        float rstd = rsqrtf(sums[64 + b] * (1.f / 1048576.f) - mean * mean + LN_EPS);
        const float4* xp = (const float4*)(inp + (size_t)b * 1048576 + n * 256 + dcol);
        float4 v0 = xp[0], v1 = xp[1];
        ushort o[8];
        o[0] = f2bf((v0.x - mean) * rstd * w0.x + c0.x);
        o[1] = f2bf((v0.y - mean) * rstd * w0.y + c0.y);
        o[2] = f2bf((v0.z - mean) * rstd * w0.z + c0.z);
        o[3] = f2bf((v0.w - mean) * rstd * w0.w + c0.w);
        o[4] = f2bf((v1.x - mean) * rstd * w1.x + c1.x);
        o[5] = f2bf((v1.y - mean) * rstd * w1.y + c1.y);
        o[6] = f2bf((v1.z - mean) * rstd * w1.z + c1.z);
        o[7] = f2bf((v1.w - mean) * rstd * w1.w + c1.w);
        *(short8*)(xgs + ((size_t)((b * 256 + ntile) * 8 + ds) * 64 + lane) * 8) = *(short8*)o;
    }
}

// ---------------- per-iter: MFMA version of kq ---------------------------------------
// LN1(slots) -> q' = (sl@qW^T + qb)/16 -> qk = q'@kW, all via 16x16x32 MFMA.
__global__ void kqm(const float* __restrict__ slots, const float* __restrict__ ln1w,
                    const float* __restrict__ ln1b, const ushort* __restrict__ qWc,
                    const float* __restrict__ qb, const ushort* __restrict__ kWT,
                    const float* __restrict__ kb,
                    ushort* __restrict__ qkf, float* __restrict__ qkb,
                    float* __restrict__ denom) {
    int b = blockIdx.x, t = threadIdx.x;
    int lane = t & 63, w = t >> 6, l15 = lane & 15, quad = lane >> 4;
    __shared__ ushort slb[16 * 264];    // bf16 LN1'd slots [s][d], pitch 264 (16B rows)
    __shared__ ushort qsb[16 * 264];    // bf16 q'     [s][e]
    __shared__ ushort qkl[16 * 264];    // bf16 qk     [s][d]
    __shared__ float  qsf[16 * 260];    // f32  q' for qkb
    __shared__ float  r1[256], r2[256];

    // ---- LN1 ----
    const float* sp = slots + b * 4096;
    float vals[16]; float s = 0.f, sq = 0.f;
    #pragma unroll
    for (int k = 0; k < 16; k++) { float v = sp[k * 256 + t]; vals[k] = v; s += v; sq += v * v; }
    r1[t] = s; r2[t] = sq; __syncthreads();
    for (int st = 128; st > 0; st >>= 1) {
        if (t < st) { r1[t] += r1[t + st]; r2[t] += r2[t + st]; }
        __syncthreads();
    }
    float m  = r1[0] * (1.f / 4096.f);
    float rs = rsqrtf(r2[0] * (1.f / 4096.f) - m * m + LN_EPS);
    #pragma unroll
    for (int k = 0; k < 16; k++)
        slb[k * 264 + t] = f2bf((vals[k] - m) * rs * ln1w[k * 256 + t] + ln1b[k * 256 + t]);
    __syncthreads();

    // ---- pass1: q'[s,e] = (sum_d sl[s,d]*qW[e,d] + qb[e]) / 16 ----
    short8 af[8];
    #pragma unroll
    for (int ds = 0; ds < 8; ds++)
        af[ds] = *(const short8*)(&slb[l15 * 264 + ds * 32 + quad * 8]);
    #pragma unroll
    for (int p = 0; p < 4; p++) {
        int et = w * 4 + p;
        f32x4 c = f32x4{0.f, 0.f, 0.f, 0.f};
        #pragma unroll
        for (int ds = 0; ds < 8; ds++) {
            short8 bf_ = *(const short8*)(qWc + (size_t)(et * 16 + l15) * 256 + ds * 32 + quad * 8);
            c = __builtin_amdgcn_mfma_f32_16x16x32_bf16(af[ds], bf_, c, 0, 0, 0);
        }
        float qbv = qb[et * 16 + l15];
        #pragma unroll
        for (int r = 0; r < 4; r++) {
            float val = (c[r] + qbv) * (1.f / 16.f);
            qsf[(quad * 4 + r) * 260 + et * 16 + l15] = val;
            qsb[(quad * 4 + r) * 264 + et * 16 + l15] = f2bf(val);
        }
    }
    __syncthreads();

    // ---- qkb[s] = q'[s,:] . kb  (16 lanes per s, shfl reduce) ----
    {
        int ss = w * 4 + quad;          // s handled by this 16-lane group
        float pp = 0.f;
        #pragma unroll
        for (int e = 0; e < 16; e++) pp += qsf[ss * 260 + l15 * 16 + e] * kb[l15 * 16 + e];
        pp += __shfl_xor(pp, 1); pp += __shfl_xor(pp, 2);
        pp += __shfl_xor(pp, 4); pp += __shfl_xor(pp, 8);
        if (l15 == 0) qkb[b * 16 + ss] = pp;
    }
    if (t < 16) denom[b * 16 + t] = 0.f;

    // ---- pass2: qk[s,d] = sum_e q'[s,e]*kW[e,d]  (B from kWT[d][e]) ----
    short8 af2[8];
    #pragma unroll
    for (int es = 0; es < 8; es++)
        af2[es] = *(const short8*)(&qsb[l15 * 264 + es * 32 + quad * 8]);
    #pragma unroll
    for (int p = 0; p < 4; p++) {
        int dt = w * 4 + p;
        f32x4 c2 = f32x4{0.f, 0.f, 0.f, 0.f};
        #pragma unroll
        for (int es = 0; es < 8; es++) {
            short8 bf2 = *(const short8*)(kWT + (size_t)(dt * 16 + l15) * 256 + es * 32 + quad * 8);
            c2 = __builtin_amdgcn_mfma_f32_16x16x32_bf16(af2[es], bf2, c2, 0, 0, 0);
        }
        #pragma unroll
        for (int r = 0; r < 4; r++)
            qkl[(quad * 4 + r) * 264 + dt * 16 + l15] = f2bf(c2[r]);
    }
    __syncthreads();

    // ---- qkf: re-read qkl rows in A-frag order; wave w stores ds = w*2, w*2+1 ----
    #pragma unroll
    for (int i = 0; i < 2; i++) {
        int ds = w * 2 + i;
        short8 v = *(const short8*)(&qkl[l15 * 264 + ds * 32 + quad * 8]);
        *(short8*)(qkf + (size_t)(b * 8 + ds) * 512 + lane * 8) = v;
    }
}

// ---------------- THE hot kernel: dist = qk@x^T (+qkb) -> softmax -> ax = attn@x -----
// grid = B*16; 4 waves. dist consumes prefetch regs pf directly. ax B-frags come from
// xtT: x^T staged in EXACT ax-B-frag order via in-register MFMA-identity transpose
// (D = A*I is exact; bf16 truncate of bf16-representable values is exact).
// xtT element (frag = dtile*2+ns, lane L, j) = x[n=ns*32+(L>>4)*8+j][d=dtile*16+(L&15)]
// Writer (w,quad,l15) holds C-frag D[n=w*16+quad*4+r][d=ds*32+half*16+l15] ->
//   addr = (ds*2+half)*1024 + (w>>1)*512 + ((w*2+(quad>>1))&3)*128 + l15*8 + (quad&1)*4 + r
// (bijection verified element-wise).
__launch_bounds__(256, 4)
__global__ void katt(const ushort* __restrict__ xgs, const ushort* __restrict__ qkf,
                     const float* __restrict__ qkb, float* __restrict__ denom,
                     float* __restrict__ partials) {
    int b = blockIdx.x >> 4, chunk = blockIdx.x & 15;
    int tid = threadIdx.x;
    int lane = tid & 63, w = tid >> 6;
    int l15 = lane & 15, quad = lane >> 4;

    __shared__ ushort xtT[16384];       // x^T in ax-B-frag order (32 KB)
    __shared__ ushort attn[16 * 72];    // attn [s][n_local], pitch 72

    // identity B-frags for MFMA transpose: Ilo[k][c]=d(k,c), Ihi[k][c]=d(k,c+16)
    short8 ilo, ihi;
    #pragma unroll
    for (int j = 0; j < 8; j++) {
        ilo[j] = (short)((quad * 8 + j == l15)      ? 0x3F80 : 0);
        ihi[j] = (short)((quad * 8 + j == l15 + 16) ? 0x3F80 : 0);
    }
    int wbase = (w >> 1) * 512 + ((w * 2 + (quad >> 1)) & 3) * 128 + l15 * 8 + (quad & 1) * 4;

    short8 qkfr[8];
    #pragma unroll
    for (int ds = 0; ds < 8; ds++)
        qkfr[ds] = *(const short8*)(qkf + ((size_t)(b * 8 + ds) * 512 + lane * 8));
    float4 qo = *(const float4*)(qkb + b * 16 + quad * 4);

    f32x4 pacc[4];
    #pragma unroll
    for (int u = 0; u < 4; u++) pacc[u] = f32x4{0.f, 0.f, 0.f, 0.f};
    float dp0 = 0.f, dp1 = 0.f, dp2 = 0.f, dp3 = 0.f;

    int tile0 = b * 256 + chunk * 16;

    short8 pf[8];
    #pragma unroll
    for (int i = 0; i < 8; i++)
        pf[i] = *(const short8*)(xgs + (((size_t)(tile0 + w) * 8 + i) * 64 + lane) * 8);

    #pragma unroll 1
    for (int sub = 0; sub < 4; sub++) {
        __syncthreads();                // prior ax done reading xtT/attn
        // ===== dist from pf =====
        f32x4 dc = f32x4{0.f, 0.f, 0.f, 0.f};
        #pragma unroll
        for (int ds = 0; ds < 8; ds++)
            dc = __builtin_amdgcn_mfma_f32_16x16x32_bf16(qkfr[ds], pf[ds], dc, 0, 0, 0);
        dc[0] += qo.x; dc[1] += qo.y; dc[2] += qo.z; dc[3] += qo.w;
        float mx = fmaxf(fmaxf(dc[0], dc[1]), fmaxf(dc[2], dc[3]));
        mx = fmaxf(mx, __shfl_xor(mx, 16));
        mx = fmaxf(mx, __shfl_xor(mx, 32));
        float e0 = __expf(dc[0] - mx), e1 = __expf(dc[1] - mx);
        float e2 = __expf(dc[2] - mx), e3 = __expf(dc[3] - mx);
        float lsum = e0 + e1 + e2 + e3;
        lsum += __shfl_xor(lsum, 16); lsum += __shfl_xor(lsum, 32);
        float inv = 1.f / lsum;
        float p0 = e0 * inv, p1 = e1 * inv, p2 = e2 * inv, p3 = e3 * inv;
        dp0 += p0; dp1 += p1; dp2 += p2; dp3 += p3;
        attn[(quad * 4 + 0) * 72 + w * 16 + l15] = f2bf(p0);
        attn[(quad * 4 + 1) * 72 + w * 16 + l15] = f2bf(p1);
        attn[(quad * 4 + 2) * 72 + w * 16 + l15] = f2bf(p2);
        attn[(quad * 4 + 3) * 72 + w * 16 + l15] = f2bf(p3);
        // ===== transpose pf -> xtT (B-frag order) =====
        f32x4 zz = f32x4{0.f, 0.f, 0.f, 0.f};
        #pragma unroll
        for (int ds = 0; ds < 8; ds++) {
            f32x4 tlo = __builtin_amdgcn_mfma_f32_16x16x32_bf16(pf[ds], ilo, zz, 0, 0, 0);
            f32x4 thi = __builtin_amdgcn_mfma_f32_16x16x32_bf16(pf[ds], ihi, zz, 0, 0, 0);
            unsigned lo0 = (__float_as_uint(tlo[0]) >> 16) | (__float_as_uint(tlo[1]) & 0xFFFF0000u);
            unsigned lo1 = (__float_as_uint(tlo[2]) >> 16) | (__float_as_uint(tlo[3]) & 0xFFFF0000u);
            unsigned hi0 = (__float_as_uint(thi[0]) >> 16) | (__float_as_uint(thi[1]) & 0xFFFF0000u);
            unsigned hi1 = (__float_as_uint(thi[2]) >> 16) | (__float_as_uint(thi[3]) & 0xFFFF0000u);
            *(uint2*)(&xtT[(ds * 2 + 0) * 1024 + wbase]) = make_uint2(lo0, lo1);
            *(uint2*)(&xtT[(ds * 2 + 1) * 1024 + wbase]) = make_uint2(hi0, hi1);
        }
        if (sub < 3) {                  // pf dead after dist+transpose -> prefetch next
            #pragma unroll
            for (int i = 0; i < 8; i++)
                pf[i] = *(const short8*)(xgs + (((size_t)(tile0 + (sub + 1) * 4 + w) * 8 + i) * 64 + lane) * 8);
        }
        __syncthreads();                // xtT + attn visible to all waves

        // ===== ax: pacc[s][d] += sum_n attn[s,n]*x[n,d]; wave w owns d [w*64,(w+1)*64) =====
        #pragma unroll
        for (int ns = 0; ns < 2; ns++) {
            short8 aa = *(const short8*)(&attn[l15 * 72 + ns * 32 + quad * 8]);
            #pragma unroll
            for (int u = 0; u < 4; u++) {
                short8 bb = *(const short8*)(&xtT[((w * 4 + u) * 2 + ns) * 512 + lane * 8]);
                pacc[u] = __builtin_amdgcn_mfma_f32_16x16x32_bf16(aa, bb, pacc[u], 0, 0, 0);
            }
        }
    }

    #pragma unroll
    for (int m = 1; m < 16; m <<= 1) {
        dp0 += __shfl_xor(dp0, m); dp1 += __shfl_xor(dp1, m);
        dp2 += __shfl_xor(dp2, m); dp3 += __shfl_xor(dp3, m);
    }
    if (l15 == 0) {
        atomicAdd(&denom[b * 16 + quad * 4 + 0], dp0);
        atomicAdd(&denom[b * 16 + quad * 4 + 1], dp1);
        atomicAdd(&denom[b * 16 + quad * 4 + 2], dp2);
        atomicAdd(&denom[b * 16 + quad * 4 + 3], dp3);
    }

    float* pout = partials + (size_t)(b * 16 + chunk) * 4096;   // [s][d]
    #pragma unroll
    for (int u = 0; u < 4; u++)
        #pragma unroll
        for (int r = 0; r < 4; r++)
            pout[(quad * 4 + r) * 256 + (w * 4 + u) * 16 + l15] = pacc[u][r];
}

// ---------------- reduce chunks + apply vW^T + vb, divide by denom -------------------
__global__ void kred2(const float* __restrict__ partials, const float* __restrict__ denom,
                      const ushort* __restrict__ vWT, const float* __restrict__ vb,
                      float* __restrict__ slots) {
    int b = blockIdx.x >> 2, dq = blockIdx.x & 3, t = threadIdx.x;
    __shared__ float axs[4096];
    __shared__ float dn[16];
    #pragma unroll
    for (int i = 0; i < 16; i++) {
        int idx = i * 256 + t;
        float ssum = 0.f;
        #pragma unroll
        for (int c = 0; c < 16; c++) ssum += partials[(size_t)b * 65536 + c * 4096 + idx];
        axs[idx] = ssum;
    }
    if (t < 16) dn[t] = denom[b * 16 + t];
    __syncthreads();
    int d = dq * 64 + (t & 63), sg = t >> 6;
    float acc[4];
    #pragma unroll
    for (int i = 0; i < 4; i++) acc[i] = 0.f;
    for (int e = 0; e < 256; e++) {
        float wv = bf2f(vWT[e * 256 + d]);
        #pragma unroll
        for (int i = 0; i < 4; i++) acc[i] += axs[(sg + i * 4) * 256 + e] * wv;
    }
    float vbd = vb[d];
    #pragma unroll
    for (int i = 0; i < 4; i++) {
        int s = sg + i * 4;
        float A = dn[s];
        slots[b * 4096 + s * 256 + d] = (acc[i] + vbd * A) / (A + 1e-7f);
    }
}

// ---------------- LN2 + MLP layer 1 (relu) -> htmp bf16 ------------------------------
__global__ void kfin1(const float* __restrict__ slots_in, const float* __restrict__ ln2w,
                      const float* __restrict__ ln2b, const ushort* __restrict__ m1WT,
                      const float* __restrict__ m1b, ushort* __restrict__ htmp) {
    int b = blockIdx.x >> 2, hq = blockIdx.x & 3, t = threadIdx.x;
    __shared__ float s2[4096];
    __shared__ float r1[256], r2[256];
    const float* sp = slots_in + b * 4096;
    float vals[16]; float s = 0.f, sq = 0.f;
    #pragma unroll
    for (int k = 0; k < 16; k++) { float v = sp[k * 256 + t]; vals[k] = v; s += v; sq += v * v; }
    r1[t] = s; r2[t] = sq; __syncthreads();
    for (int st = 128; st > 0; st >>= 1) {
        if (t < st) { r1[t] += r1[t + st]; r2[t] += r2[t + st]; }
        __syncthreads();
    }
    float m  = r1[0] * (1.f / 4096.f);
    float rs = rsqrtf(r2[0] * (1.f / 4096.f) - m * m + LN_EPS);
    #pragma unroll
    for (int k = 0; k < 16; k++)
        s2[k * 256 + t] = (vals[k] - m) * rs * ln2w[k * 256 + t] + ln2b[k * 256 + t];
    __syncthreads();
    int j = hq * 128 + (t & 127), sg2 = t >> 7;
    float acc[8];
    #pragma unroll
    for (int i = 0; i < 8; i++) acc[i] = 0.f;
    for (int d = 0; d < 256; d++) {
        float wv = bf2f(m1WT[d * 512 + j]);
        #pragma unroll
        for (int i = 0; i < 8; i++) acc[i] += s2[(sg2 + i * 2) * 256 + d] * wv;
    }
    float bias = m1b[j];
    #pragma unroll
    for (int i = 0; i < 8; i++)
        htmp[b * 8192 + (sg2 + i * 2) * 512 + j] = f2bf(fmaxf(acc[i] + bias, 0.f));
}

// ---------------- MLP layer 2 + residual ---------------------------------------------
__global__ void kfin2(const ushort* __restrict__ htmp, const ushort* __restrict__ m2WT,
                      const float* __restrict__ m2b, float* __restrict__ slots,
                      float* __restrict__ final_out, int write_final) {
    int b = blockIdx.x >> 2, dq = blockIdx.x & 3, t = threadIdx.x;
    __shared__ float hl[8192];
    #pragma unroll
    for (int i = 0; i < 32; i++) {
        int idx = i * 256 + t;
        hl[idx] = bf2f(htmp[b * 8192 + idx]);
    }
    __syncthreads();
    int d = dq * 64 + (t & 63), sg = t >> 6;
    float acc[4];
    #pragma unroll
    for (int i = 0; i < 4; i++) acc[i] = 0.f;
    for (int j = 0; j < 512; j++) {
        float wv = bf2f(m2WT[j * 256 + d]);
        #pragma unroll
        for (int i = 0; i < 4; i++) acc[i] += hl[(sg + i * 4) * 512 + j] * wv;
    }
    float bias2 = m2b[d];
    #pragma unroll
    for (int i = 0; i < 4; i++) {
        int s = sg + i * 4;
        float raw = slots[b * 4096 + s * 256 + d];
        float val = raw + acc[i] + bias2;
        slots[b * 4096 + s * 256 + d] = val;
        if (write_final) final_out[b * 4096 + s * 256 + d] = val;
    }
}

extern "C" void kernel_launch(void* const* d_in, const int* in_sizes, int n_in,
                              void* d_out, int out_size, void* d_ws, size_t ws_size,
                              hipStream_t stream) {
    const float* inputs     = (const float*)d_in[0];
    const float* slots_init = (const float*)d_in[1];
    const float* mu         = (const float*)d_in[2];
    const float* logsig     = (const float*)d_in[3];
    const float* ln0w       = (const float*)d_in[4];
    const float* ln0b       = (const float*)d_in[5];
    const float* ln1w       = (const float*)d_in[6];
    const float* ln1b       = (const float*)d_in[7];
    const float* ln2w       = (const float*)d_in[8];
    const float* ln2b       = (const float*)d_in[9];
    const float* qW         = (const float*)d_in[10];
    const float* qb         = (const float*)d_in[11];
    const float* kW         = (const float*)d_in[12];
    const float* kb         = (const float*)d_in[13];
    const float* vW         = (const float*)d_in[14];
    const float* vb         = (const float*)d_in[15];
    const float* m1W        = (const float*)d_in[16];
    const float* m1b        = (const float*)d_in[17];
    const float* m2W        = (const float*)d_in[18];
    const float* m2b        = (const float*)d_in[19];

    char* ws = (char*)d_ws;
    ushort* xgs     = (ushort*)(ws);                   // 134,217,728 B
    float*  partials= (float*)(ws + 134217728);        //  16,777,216 B
    ushort* qkf     = (ushort*)(ws + 150994944);       //     524,288 B
    ushort* htmp    = (ushort*)(ws + 151519232);       //   1,048,576 B
    float*  slots   = (float*)(ws + 152567808);        //   1,048,576 B
    ushort* qWc     = (ushort*)(ws + 153616384);       //     393,216 B
    ushort* m1WT    = (ushort*)(ws + 154009600);       //     786,432 B
    ushort* m2WT    = (ushort*)(ws + 154796032);       //     786,432 B
    ushort* vWT     = (ushort*)(ws + 155582464);       //     393,216 B
    float*  denom   = (float*)(ws + 155975680);        //       4,096 B
    float*  qkb     = (float*)(ws + 155979776);        //       4,096 B
    float*  sums    = (float*)(ws + 155983872);        //         512 B (pad to 155,984,384)
    ushort* kWT     = (ushort*)(ws + 155984384);       //     393,216 B
    // total 156,377,600 B <= 157,295,104 B proven available

    kinit<<<1024, 256, 0, stream>>>(slots_init, mu, logsig, slots, sums);
    ktrans<<<336, 256, 0, stream>>>(qW, kW, m1W, m2W, vW, qWc, kWT, m1WT, m2WT, vWT);
    l0a<<<2048, 256, 0, stream>>>(inputs, sums);
    l0bs<<<1024, 256, 0, stream>>>(inputs, ln0w, ln0b, sums, xgs);

    for (int it = 0; it < 3; it++) {
        kqm<<<64, 256, 0, stream>>>(slots, ln1w, ln1b, qWc + it * 65536, qb + it * 256,
                                    kWT + it * 65536, kb + it * 256, qkf, qkb, denom);
        katt<<<1024, 256, 0, stream>>>(xgs, qkf, qkb, denom, partials);
        kred2<<<256, 256, 0, stream>>>(partials, denom, vWT + it * 65536, vb + it * 256, slots);
        kfin1<<<256, 256, 0, stream>>>(slots, ln2w, ln2b, m1WT + it * 131072, m1b + it * 512, htmp);
        kfin2<<<256, 256, 0, stream>>>(htmp, m2WT + it * 131072, m2b + it * 256, slots,
                                       (float*)d_out, it == 2 ? 1 : 0);
    }
}

// Round 8
// 384.396 us; speedup vs baseline: 1.5058x; 1.5054x over previous
//
#include <hip/hip_runtime.h>
#include <hip/hip_bf16.h>

#define LN_EPS 1e-5f

typedef __attribute__((ext_vector_type(8))) short short8;   // 8 bf16
typedef __attribute__((ext_vector_type(4))) float f32x4;    // MFMA C/D frag

__device__ __forceinline__ ushort f2bf(float f) {
    __hip_bfloat16 h = __float2bfloat16(f);
    return *reinterpret_cast<ushort*>(&h);
}
__device__ __forceinline__ float bf2f(ushort u) {
    union { float f; unsigned int i; } c; c.i = ((unsigned int)u) << 16; return c.f;
}

// ---------------- init: slots0 = mu + exp(logsigma)*slots_init; zero LN0 sums --------
__global__ void kinit(const float* __restrict__ slots_init, const float* __restrict__ mu,
                      const float* __restrict__ logsig, float* __restrict__ slots,
                      float* __restrict__ sums) {
    int i = blockIdx.x * 256 + threadIdx.x;    // 262144 exactly
    int d = i & 255;
    slots[i] = mu[d] + __expf(logsig[d]) * slots_init[i];
    if (blockIdx.x == 0 && threadIdx.x < 128) sums[threadIdx.x] = 0.f;
}

// ---------------- weight prep --------------------------------------------------------
// Straight bf16 casts (MFMA B-frags read weight ROWS, K contiguous):
//   blk 0-47   : qWc[e][d]  = qW    (3 x 256x256)
//   blk 48-95  : vWc[e][d]  = vW    (3 x 256x256)
//   blk 96-191 : m1Wc[j][d] = m1W   (3 x 512x256)
//   blk 192-287: m2Wc[d][j] = m2W   (3 x 256x512)
// Transpose:
//   blk 288-335: kWT[d][e]  = kW[e][d]
__global__ void ktrans(const float* __restrict__ qW, const float* __restrict__ kW,
                       const float* __restrict__ m1W, const float* __restrict__ m2W,
                       const float* __restrict__ vW,
                       ushort* __restrict__ qWc, ushort* __restrict__ kWT,
                       ushort* __restrict__ m1Wc, ushort* __restrict__ m2Wc,
                       ushort* __restrict__ vWc) {
    int blk = blockIdx.x, t = threadIdx.x;
    int col = t & 63, rq = t >> 6;
    if (blk < 288) {   // straight 64x64-tile casts
        const float* src; ushort* dst; int C, tr, tc;
        if (blk < 48)        { int it = blk >> 4, rem = blk & 15; C = 256; tr = rem >> 2; tc = rem & 3;
                               src = qW + it * 65536;  dst = qWc + it * 65536; }
        else if (blk < 96)   { int li = blk - 48; int it = li >> 4, rem = li & 15; C = 256; tr = rem >> 2; tc = rem & 3;
                               src = vW + it * 65536;  dst = vWc + it * 65536; }
        else if (blk < 192)  { int li = blk - 96; int it = li >> 5, rem = li & 31; C = 256; tr = rem >> 2; tc = rem & 3;
                               src = m1W + it * 131072; dst = m1Wc + it * 131072; }
        else                 { int li = blk - 192; int it = li >> 5, rem = li & 31; C = 512; tr = rem >> 3; tc = rem & 7;
                               src = m2W + it * 131072; dst = m2Wc + it * 131072; }
        #pragma unroll
        for (int r = 0; r < 16; r++) {
            int row = r * 4 + rq;
            int idx = (tr * 64 + row) * C + tc * 64 + col;
            dst[idx] = f2bf(src[idx]);
        }
        return;
    }
    __shared__ float tile[64][65];
    int li = blk - 288; int it = li >> 4, rem = li & 15;
    int tr = rem >> 2, tc = rem & 3;
    const float* src = kW + it * 65536; ushort* dst = kWT + it * 65536;
    #pragma unroll
    for (int r = 0; r < 16; r++) {
        int row = r * 4 + rq;
        tile[row][col] = src[(tr * 64 + row) * 256 + tc * 64 + col];
    }
    __syncthreads();
    #pragma unroll
    for (int r = 0; r < 16; r++) {
        int row = r * 4 + rq;
        dst[(tc * 64 + row) * 256 + tr * 64 + col] = f2bf(tile[col][row]);
    }
}

// ---------------- LN0 pass 1: per-batch sum/sumsq over N*DIN = 1M elems -------------
__global__ void l0a(const float* __restrict__ inp, float* __restrict__ sums) {
    int b = blockIdx.x >> 5, seg = blockIdx.x & 31;
    const float4* p = (const float4*)inp + (size_t)b * 262144 + seg * 8192 + threadIdx.x;
    float s = 0.f, sq = 0.f;
    #pragma unroll
    for (int k = 0; k < 32; k++) {
        float4 v = p[k * 256];
        s  += v.x + v.y + v.z + v.w;
        sq += v.x * v.x + v.y * v.y + v.z * v.z + v.w * v.w;
    }
    __shared__ float r1[256], r2[256];
    r1[threadIdx.x] = s; r2[threadIdx.x] = sq; __syncthreads();
    for (int st = 128; st > 0; st >>= 1) {
        if (threadIdx.x < st) { r1[threadIdx.x] += r1[threadIdx.x + st]; r2[threadIdx.x] += r2[threadIdx.x + st]; }
        __syncthreads();
    }
    if (threadIdx.x == 0) { atomicAdd(&sums[b], r1[0]); atomicAdd(&sums[64 + b], r2[0]); }
}

// ---------------- LN0 pass 2: normalize + write bf16 x in MFMA-frag order ------------
// xgs[tile16(16384)][ds(8)][lane(64)][j(8)]: x[tile16*16+(lane&15)][ds*32+(lane>>4)*8+j]
__global__ void l0bs(const float* __restrict__ inp, const float* __restrict__ ln0w,
                     const float* __restrict__ ln0b, const float* __restrict__ sums,
                     ushort* __restrict__ xgs) {
    int gw = blockIdx.x * 4 + (threadIdx.x >> 6);     // 4096 wave tasks
    int lane = threadIdx.x & 63, l15 = lane & 15, quad = lane >> 4;
    int ntile = gw >> 4;                              // 0..255 (within-batch 16-token tile)
    int ds = (gw >> 1) & 7;
    int b0 = (gw & 1) * 32;
    int n = ntile * 16 + l15;                         // within-batch token
    int dcol = ds * 32 + quad * 8;
    const float4* wp = (const float4*)(ln0w + n * 256 + dcol);
    const float4* bp = (const float4*)(ln0b + n * 256 + dcol);
    float4 w0 = wp[0], w1 = wp[1];
    float4 c0 = bp[0], c1 = bp[1];
    #pragma unroll 4
    for (int bi = 0; bi < 32; bi++) {
        int b = b0 + bi;
        float mean = sums[b] * (1.f / 1048576.f);
        float rstd = rsqrtf(sums[64 + b] * (1.f / 1048576.f) - mean * mean + LN_EPS);
        const float4* xp = (const float4*)(inp + (size_t)b * 1048576 + n * 256 + dcol);
        float4 v0 = xp[0], v1 = xp[1];
        ushort o[8];
        o[0] = f2bf((v0.x - mean) * rstd * w0.x + c0.x);
        o[1] = f2bf((v0.y - mean) * rstd * w0.y + c0.y);
        o[2] = f2bf((v0.z - mean) * rstd * w0.z + c0.z);
        o[3] = f2bf((v0.w - mean) * rstd * w0.w + c0.w);
        o[4] = f2bf((v1.x - mean) * rstd * w1.x + c1.x);
        o[5] = f2bf((v1.y - mean) * rstd * w1.y + c1.y);
        o[6] = f2bf((v1.z - mean) * rstd * w1.z + c1.z);
        o[7] = f2bf((v1.w - mean) * rstd * w1.w + c1.w);
        *(short8*)(xgs + ((size_t)((b * 256 + ntile) * 8 + ds) * 64 + lane) * 8) = *(short8*)o;
    }
}

// ---------------- initial q-gen (it=0 only): LN1 -> q' -> qk, MFMA -------------------
__global__ void kqm(const float* __restrict__ slots, const float* __restrict__ ln1w,
                    const float* __restrict__ ln1b, const ushort* __restrict__ qWc,
                    const float* __restrict__ qb, const ushort* __restrict__ kWT,
                    const float* __restrict__ kb,
                    ushort* __restrict__ qkf, float* __restrict__ qkb,
                    float* __restrict__ denom) {
    int b = blockIdx.x, t = threadIdx.x;
    int lane = t & 63, w = t >> 6, l15 = lane & 15, quad = lane >> 4;
    __shared__ ushort slb[16 * 264];
    __shared__ ushort qsb[16 * 264];
    __shared__ ushort qkl[16 * 264];
    __shared__ float  qsf[16 * 260];
    __shared__ float  r1[256], r2[256];

    const float* sp = slots + b * 4096;
    float vals[16]; float s = 0.f, sq = 0.f;
    #pragma unroll
    for (int k = 0; k < 16; k++) { float v = sp[k * 256 + t]; vals[k] = v; s += v; sq += v * v; }
    r1[t] = s; r2[t] = sq; __syncthreads();
    for (int st = 128; st > 0; st >>= 1) {
        if (t < st) { r1[t] += r1[t + st]; r2[t] += r2[t + st]; }
        __syncthreads();
    }
    float m  = r1[0] * (1.f / 4096.f);
    float rs = rsqrtf(r2[0] * (1.f / 4096.f) - m * m + LN_EPS);
    #pragma unroll
    for (int k = 0; k < 16; k++)
        slb[k * 264 + t] = f2bf((vals[k] - m) * rs * ln1w[k * 256 + t] + ln1b[k * 256 + t]);
    __syncthreads();

    short8 af[8];
    #pragma unroll
    for (int ds = 0; ds < 8; ds++)
        af[ds] = *(const short8*)(&slb[l15 * 264 + ds * 32 + quad * 8]);
    #pragma unroll
    for (int p = 0; p < 4; p++) {
        int et = w * 4 + p;
        f32x4 c = f32x4{0.f, 0.f, 0.f, 0.f};
        #pragma unroll
        for (int ds = 0; ds < 8; ds++) {
            short8 bf_ = *(const short8*)(qWc + (size_t)(et * 16 + l15) * 256 + ds * 32 + quad * 8);
            c = __builtin_amdgcn_mfma_f32_16x16x32_bf16(af[ds], bf_, c, 0, 0, 0);
        }
        float qbv = qb[et * 16 + l15];
        #pragma unroll
        for (int r = 0; r < 4; r++) {
            float val = (c[r] + qbv) * (1.f / 16.f);
            qsf[(quad * 4 + r) * 260 + et * 16 + l15] = val;
            qsb[(quad * 4 + r) * 264 + et * 16 + l15] = f2bf(val);
        }
    }
    __syncthreads();

    {
        int ss = w * 4 + quad;
        float pp = 0.f;
        #pragma unroll
        for (int e = 0; e < 16; e++) pp += qsf[ss * 260 + l15 * 16 + e] * kb[l15 * 16 + e];
        pp += __shfl_xor(pp, 1); pp += __shfl_xor(pp, 2);
        pp += __shfl_xor(pp, 4); pp += __shfl_xor(pp, 8);
        if (l15 == 0) qkb[b * 16 + ss] = pp;
    }
    if (t < 16) denom[b * 16 + t] = 0.f;

    short8 af2[8];
    #pragma unroll
    for (int es = 0; es < 8; es++)
        af2[es] = *(const short8*)(&qsb[l15 * 264 + es * 32 + quad * 8]);
    #pragma unroll
    for (int p = 0; p < 4; p++) {
        int dt = w * 4 + p;
        f32x4 c2 = f32x4{0.f, 0.f, 0.f, 0.f};
        #pragma unroll
        for (int es = 0; es < 8; es++) {
            short8 bf2 = *(const short8*)(kWT + (size_t)(dt * 16 + l15) * 256 + es * 32 + quad * 8);
            c2 = __builtin_amdgcn_mfma_f32_16x16x32_bf16(af2[es], bf2, c2, 0, 0, 0);
        }
        #pragma unroll
        for (int r = 0; r < 4; r++)
            qkl[(quad * 4 + r) * 264 + dt * 16 + l15] = f2bf(c2[r]);
    }
    __syncthreads();

    #pragma unroll
    for (int i = 0; i < 2; i++) {
        int ds = w * 2 + i;
        short8 v = *(const short8*)(&qkl[l15 * 264 + ds * 32 + quad * 8]);
        *(short8*)(qkf + (size_t)(b * 8 + ds) * 512 + lane * 8) = v;
    }
}

// ---------------- THE hot kernel: dist = qk@x^T (+qkb) -> softmax -> ax = attn@x -----
// (unchanged from R7: dist from regs, MFMA-identity transpose for ax B-frags)
__launch_bounds__(256, 4)
__global__ void katt(const ushort* __restrict__ xgs, const ushort* __restrict__ qkf,
                     const float* __restrict__ qkb, float* __restrict__ denom,
                     float* __restrict__ partials) {
    int b = blockIdx.x >> 4, chunk = blockIdx.x & 15;
    int tid = threadIdx.x;
    int lane = tid & 63, w = tid >> 6;
    int l15 = lane & 15, quad = lane >> 4;

    __shared__ ushort xtT[16384];       // x^T in ax-B-frag order (32 KB)
    __shared__ ushort attn[16 * 72];    // attn [s][n_local], pitch 72

    short8 ilo, ihi;
    #pragma unroll
    for (int j = 0; j < 8; j++) {
        ilo[j] = (short)((quad * 8 + j == l15)      ? 0x3F80 : 0);
        ihi[j] = (short)((quad * 8 + j == l15 + 16) ? 0x3F80 : 0);
    }
    int wbase = (w >> 1) * 512 + ((w * 2 + (quad >> 1)) & 3) * 128 + l15 * 8 + (quad & 1) * 4;

    short8 qkfr[8];
    #pragma unroll
    for (int ds = 0; ds < 8; ds++)
        qkfr[ds] = *(const short8*)(qkf + ((size_t)(b * 8 + ds) * 512 + lane * 8));
    float4 qo = *(const float4*)(qkb + b * 16 + quad * 4);

    f32x4 pacc[4];
    #pragma unroll
    for (int u = 0; u < 4; u++) pacc[u] = f32x4{0.f, 0.f, 0.f, 0.f};
    float dp0 = 0.f, dp1 = 0.f, dp2 = 0.f, dp3 = 0.f;

    int tile0 = b * 256 + chunk * 16;

    short8 pf[8];
    #pragma unroll
    for (int i = 0; i < 8; i++)
        pf[i] = *(const short8*)(xgs + (((size_t)(tile0 + w) * 8 + i) * 64 + lane) * 8);

    #pragma unroll 1
    for (int sub = 0; sub < 4; sub++) {
        __syncthreads();
        f32x4 dc = f32x4{0.f, 0.f, 0.f, 0.f};
        #pragma unroll
        for (int ds = 0; ds < 8; ds++)
            dc = __builtin_amdgcn_mfma_f32_16x16x32_bf16(qkfr[ds], pf[ds], dc, 0, 0, 0);
        dc[0] += qo.x; dc[1] += qo.y; dc[2] += qo.z; dc[3] += qo.w;
        float mx = fmaxf(fmaxf(dc[0], dc[1]), fmaxf(dc[2], dc[3]));
        mx = fmaxf(mx, __shfl_xor(mx, 16));
        mx = fmaxf(mx, __shfl_xor(mx, 32));
        float e0 = __expf(dc[0] - mx), e1 = __expf(dc[1] - mx);
        float e2 = __expf(dc[2] - mx), e3 = __expf(dc[3] - mx);
        float lsum = e0 + e1 + e2 + e3;
        lsum += __shfl_xor(lsum, 16); lsum += __shfl_xor(lsum, 32);
        float inv = 1.f / lsum;
        float p0 = e0 * inv, p1 = e1 * inv, p2 = e2 * inv, p3 = e3 * inv;
        dp0 += p0; dp1 += p1; dp2 += p2; dp3 += p3;
        attn[(quad * 4 + 0) * 72 + w * 16 + l15] = f2bf(p0);
        attn[(quad * 4 + 1) * 72 + w * 16 + l15] = f2bf(p1);
        attn[(quad * 4 + 2) * 72 + w * 16 + l15] = f2bf(p2);
        attn[(quad * 4 + 3) * 72 + w * 16 + l15] = f2bf(p3);
        f32x4 zz = f32x4{0.f, 0.f, 0.f, 0.f};
        #pragma unroll
        for (int ds = 0; ds < 8; ds++) {
            f32x4 tlo = __builtin_amdgcn_mfma_f32_16x16x32_bf16(pf[ds], ilo, zz, 0, 0, 0);
            f32x4 thi = __builtin_amdgcn_mfma_f32_16x16x32_bf16(pf[ds], ihi, zz, 0, 0, 0);
            unsigned lo0 = (__float_as_uint(tlo[0]) >> 16) | (__float_as_uint(tlo[1]) & 0xFFFF0000u);
            unsigned lo1 = (__float_as_uint(tlo[2]) >> 16) | (__float_as_uint(tlo[3]) & 0xFFFF0000u);
            unsigned hi0 = (__float_as_uint(thi[0]) >> 16) | (__float_as_uint(thi[1]) & 0xFFFF0000u);
            unsigned hi1 = (__float_as_uint(thi[2]) >> 16) | (__float_as_uint(thi[3]) & 0xFFFF0000u);
            *(uint2*)(&xtT[(ds * 2 + 0) * 1024 + wbase]) = make_uint2(lo0, lo1);
            *(uint2*)(&xtT[(ds * 2 + 1) * 1024 + wbase]) = make_uint2(hi0, hi1);
        }
        if (sub < 3) {
            #pragma unroll
            for (int i = 0; i < 8; i++)
                pf[i] = *(const short8*)(xgs + (((size_t)(tile0 + (sub + 1) * 4 + w) * 8 + i) * 64 + lane) * 8);
        }
        __syncthreads();

        #pragma unroll
        for (int ns = 0; ns < 2; ns++) {
            short8 aa = *(const short8*)(&attn[l15 * 72 + ns * 32 + quad * 8]);
            #pragma unroll
            for (int u = 0; u < 4; u++) {
                short8 bb = *(const short8*)(&xtT[((w * 4 + u) * 2 + ns) * 512 + lane * 8]);
                pacc[u] = __builtin_amdgcn_mfma_f32_16x16x32_bf16(aa, bb, pacc[u], 0, 0, 0);
            }
        }
    }

    #pragma unroll
    for (int m = 1; m < 16; m <<= 1) {
        dp0 += __shfl_xor(dp0, m); dp1 += __shfl_xor(dp1, m);
        dp2 += __shfl_xor(dp2, m); dp3 += __shfl_xor(dp3, m);
    }
    if (l15 == 0) {
        atomicAdd(&denom[b * 16 + quad * 4 + 0], dp0);
        atomicAdd(&denom[b * 16 + quad * 4 + 1], dp1);
        atomicAdd(&denom[b * 16 + quad * 4 + 2], dp2);
        atomicAdd(&denom[b * 16 + quad * 4 + 3], dp3);
    }

    float* pout = partials + (size_t)(b * 16 + chunk) * 4096;   // [s][d]
    #pragma unroll
    for (int u = 0; u < 4; u++)
        #pragma unroll
        for (int r = 0; r < 4; r++)
            pout[(quad * 4 + r) * 256 + (w * 4 + u) * 16 + l15] = pacc[u][r];
}

// ---------------- fused tail: partials-reduce -> v-apply -> LN2 -> MLP1 -> MLP2+res --
// -> (optional) next-iter q-gen. grid 64 (one block per batch), 256 threads.
// All GEMMs use the kqm-proven MFMA frag pattern. LDS pool phase-aliased (59 KB),
// reuses only across dead regions separated by barriers.
__global__ void ktail(const float* __restrict__ partials, const float* __restrict__ denom,
                      const ushort* __restrict__ vWc, const float* __restrict__ vb,
                      const float* __restrict__ ln2w, const float* __restrict__ ln2b,
                      const ushort* __restrict__ m1Wc, const float* __restrict__ m1b,
                      const ushort* __restrict__ m2Wc, const float* __restrict__ m2b,
                      float* __restrict__ final_out, int write_final,
                      const float* __restrict__ ln1w, const float* __restrict__ ln1b,
                      const ushort* __restrict__ qWc_n, const float* __restrict__ qb_n,
                      const ushort* __restrict__ kWT_n, const float* __restrict__ kb_n,
                      ushort* __restrict__ qkf, float* __restrict__ qkb,
                      float* __restrict__ denom_out, int gen) {
    int b = blockIdx.x, t = threadIdx.x;
    int lane = t & 63, w = t >> 6, l15 = lane & 15, quad = lane >> 4;

    __shared__ char pool[60416];
    __shared__ float dnb[16];
    ushort* axsb = (ushort*)pool;                  // [0,8448)      P1-2: ax bf16 [16][264]
    ushort* s2b  = (ushort*)(pool + 8448);         // [8448,16896)  P2-4: LN2'd slots bf16
    float*  slt  = (float*)(pool + 16896);         // [16896,33280) P2-5: v-apply out f32 [16][256]
    float*  r1   = (float*)(pool + 33280);         // [33280,34304)
    float*  r2   = (float*)(pool + 34304);         // [34304,35328)
    ushort* hlb  = (ushort*)(pool + 35328);        // [35328,51968) P4-5: relu(h) bf16 [16][520]
    // P6 aliases (regions dead by then):
    float*  slt2 = (float*)pool;                   // [0,16384)     new slots f32
    ushort* slbq = (ushort*)(pool + 16896);        // [16896,25344) LN1'd slots bf16
    ushort* qkl  = (ushort*)(pool + 16896);        // reuse after slbq A-frags loaded
    float*  qsf  = (float*)(pool + 35328);         // [35328,51968) q' f32 [16][260]
    ushort* qsb  = (ushort*)(pool + 51968);        // [51968,60416) q' bf16 [16][264]

    // ---- P1: reduce partials chunks -> axsb (bf16, A-frag pitch) ----
    const float* pp = partials + (size_t)b * 65536;
    #pragma unroll
    for (int i = 0; i < 16; i++) {
        float ss = 0.f;
        #pragma unroll
        for (int c = 0; c < 16; c++) ss += pp[c * 4096 + i * 256 + t];
        axsb[i * 264 + t] = f2bf(ss);
    }
    if (t < 16) dnb[t] = denom[b * 16 + t];
    __syncthreads();

    // ---- P2: v-apply (MFMA): out[s,e] = sum_d ax[s,d]*vW[e,d]; slots_mid + LN2 stats
    float myv[16];
    {
        short8 af[8];
        #pragma unroll
        for (int ds = 0; ds < 8; ds++)
            af[ds] = *(const short8*)(&axsb[l15 * 264 + ds * 32 + quad * 8]);
        #pragma unroll
        for (int u = 0; u < 4; u++) {
            int et = w * 4 + u;
            f32x4 c = f32x4{0.f, 0.f, 0.f, 0.f};
            #pragma unroll
            for (int ds = 0; ds < 8; ds++) {
                short8 bf_ = *(const short8*)(vWc + (size_t)(et * 16 + l15) * 256 + ds * 32 + quad * 8);
                c = __builtin_amdgcn_mfma_f32_16x16x32_bf16(af[ds], bf_, c, 0, 0, 0);
            }
            float vbe = vb[et * 16 + l15];
            #pragma unroll
            for (int r = 0; r < 4; r++) {
                float A = dnb[quad * 4 + r];
                float val = (c[r] + vbe * A) / (A + 1e-7f);
                slt[(quad * 4 + r) * 256 + et * 16 + l15] = val;
                myv[u * 4 + r] = val;
            }
        }
    }
    {   // LN2 stats from frag-resident values (each element counted once)
        float s = 0.f, sq = 0.f;
        #pragma unroll
        for (int i = 0; i < 16; i++) { s += myv[i]; sq += myv[i] * myv[i]; }
        r1[t] = s; r2[t] = sq; __syncthreads();
        for (int st = 128; st > 0; st >>= 1) {
            if (t < st) { r1[t] += r1[t + st]; r2[t] += r2[t + st]; }
            __syncthreads();
        }
    }
    float m2_ = r1[0] * (1.f / 4096.f);
    float rs2 = rsqrtf(r2[0] * (1.f / 4096.f) - m2_ * m2_ + LN_EPS);
    #pragma unroll
    for (int u = 0; u < 4; u++) {
        int e = (w * 4 + u) * 16 + l15;
        #pragma unroll
        for (int r = 0; r < 4; r++) {
            int ss_ = quad * 4 + r;
            s2b[ss_ * 264 + e] = f2bf((myv[u * 4 + r] - m2_) * rs2 * ln2w[ss_ * 256 + e] + ln2b[ss_ * 256 + e]);
        }
    }
    __syncthreads();

    // ---- P4: MLP1 (MFMA): h[s,j] = relu(sum_d s2[s,d]*m1W[j,d] + m1b[j]) ----
    {
        short8 a2[8];
        #pragma unroll
        for (int ds = 0; ds < 8; ds++)
            a2[ds] = *(const short8*)(&s2b[l15 * 264 + ds * 32 + quad * 8]);
        #pragma unroll
        for (int p = 0; p < 8; p++) {
            int jt = w * 8 + p;
            f32x4 c = f32x4{0.f, 0.f, 0.f, 0.f};
            #pragma unroll
            for (int ds = 0; ds < 8; ds++) {
                short8 bf_ = *(const short8*)(m1Wc + (size_t)(jt * 16 + l15) * 256 + ds * 32 + quad * 8);
                c = __builtin_amdgcn_mfma_f32_16x16x32_bf16(a2[ds], bf_, c, 0, 0, 0);
            }
            float bias = m1b[jt * 16 + l15];
            #pragma unroll
            for (int r = 0; r < 4; r++)
                hlb[(quad * 4 + r) * 520 + jt * 16 + l15] = f2bf(fmaxf(c[r] + bias, 0.f));
        }
    }
    __syncthreads();

    // ---- P5: MLP2 (MFMA) + residual: slots_new = slt + h@m2W^T + m2b ----
    {
        short8 a3[16];
        #pragma unroll
        for (int js = 0; js < 16; js++)
            a3[js] = *(const short8*)(&hlb[l15 * 520 + js * 32 + quad * 8]);
        #pragma unroll
        for (int u = 0; u < 4; u++) {
            int dt = w * 4 + u;
            f32x4 c = f32x4{0.f, 0.f, 0.f, 0.f};
            #pragma unroll
            for (int js = 0; js < 16; js++) {
                short8 bf_ = *(const short8*)(m2Wc + (size_t)(dt * 16 + l15) * 512 + js * 32 + quad * 8);
                c = __builtin_amdgcn_mfma_f32_16x16x32_bf16(a3[js], bf_, c, 0, 0, 0);
            }
            float b2 = m2b[dt * 16 + l15];
            #pragma unroll
            for (int r = 0; r < 4; r++) {
                int ss_ = quad * 4 + r, d = dt * 16 + l15;
                float val = slt[ss_ * 256 + d] + c[r] + b2;
                slt2[ss_ * 256 + d] = val;
                if (write_final) final_out[(size_t)b * 4096 + ss_ * 256 + d] = val;
            }
        }
    }
    __syncthreads();

    // ---- P6: next-iter q-gen (kqm logic, slots from LDS) ----
    if (gen) {
        float vals[16]; float s = 0.f, sq = 0.f;
        #pragma unroll
        for (int k = 0; k < 16; k++) { float v = slt2[k * 256 + t]; vals[k] = v; s += v; sq += v * v; }
        r1[t] = s; r2[t] = sq; __syncthreads();
        for (int st = 128; st > 0; st >>= 1) {
            if (t < st) { r1[t] += r1[t + st]; r2[t] += r2[t + st]; }
            __syncthreads();
        }
        float m1_ = r1[0] * (1.f / 4096.f);
        float rs1 = rsqrtf(r2[0] * (1.f / 4096.f) - m1_ * m1_ + LN_EPS);
        #pragma unroll
        for (int k = 0; k < 16; k++)
            slbq[k * 264 + t] = f2bf((vals[k] - m1_) * rs1 * ln1w[k * 256 + t] + ln1b[k * 256 + t]);
        __syncthreads();

        short8 aq[8];
        #pragma unroll
        for (int ds = 0; ds < 8; ds++)
            aq[ds] = *(const short8*)(&slbq[l15 * 264 + ds * 32 + quad * 8]);
        #pragma unroll
        for (int p = 0; p < 4; p++) {
            int et = w * 4 + p;
            f32x4 c = f32x4{0.f, 0.f, 0.f, 0.f};
            #pragma unroll
            for (int ds = 0; ds < 8; ds++) {
                short8 bf_ = *(const short8*)(qWc_n + (size_t)(et * 16 + l15) * 256 + ds * 32 + quad * 8);
                c = __builtin_amdgcn_mfma_f32_16x16x32_bf16(aq[ds], bf_, c, 0, 0, 0);
            }
            float qbv = qb_n[et * 16 + l15];
            #pragma unroll
            for (int r = 0; r < 4; r++) {
                float val = (c[r] + qbv) * (1.f / 16.f);
                qsf[(quad * 4 + r) * 260 + et * 16 + l15] = val;
                qsb[(quad * 4 + r) * 264 + et * 16 + l15] = f2bf(val);
            }
        }
        __syncthreads();

        {
            int ss = w * 4 + quad;
            float pp2 = 0.f;
            #pragma unroll
            for (int e = 0; e < 16; e++) pp2 += qsf[ss * 260 + l15 * 16 + e] * kb_n[l15 * 16 + e];
            pp2 += __shfl_xor(pp2, 1); pp2 += __shfl_xor(pp2, 2);
            pp2 += __shfl_xor(pp2, 4); pp2 += __shfl_xor(pp2, 8);
            if (l15 == 0) qkb[b * 16 + ss] = pp2;
        }
        if (t < 16) denom_out[b * 16 + t] = 0.f;

        short8 aq2[8];
        #pragma unroll
        for (int es = 0; es < 8; es++)
            aq2[es] = *(const short8*)(&qsb[l15 * 264 + es * 32 + quad * 8]);
        #pragma unroll
        for (int p = 0; p < 4; p++) {
            int dt = w * 4 + p;
            f32x4 c2 = f32x4{0.f, 0.f, 0.f, 0.f};
            #pragma unroll
            for (int es = 0; es < 8; es++) {
                short8 bf2 = *(const short8*)(kWT_n + (size_t)(dt * 16 + l15) * 256 + es * 32 + quad * 8);
                c2 = __builtin_amdgcn_mfma_f32_16x16x32_bf16(aq2[es], bf2, c2, 0, 0, 0);
            }
            #pragma unroll
            for (int r = 0; r < 4; r++)
                qkl[(quad * 4 + r) * 264 + dt * 16 + l15] = f2bf(c2[r]);
        }
        __syncthreads();

        #pragma unroll
        for (int i = 0; i < 2; i++) {
            int ds = w * 2 + i;
            short8 v = *(const short8*)(&qkl[l15 * 264 + ds * 32 + quad * 8]);
            *(short8*)(qkf + (size_t)(b * 8 + ds) * 512 + lane * 8) = v;
        }
    }
}

extern "C" void kernel_launch(void* const* d_in, const int* in_sizes, int n_in,
                              void* d_out, int out_size, void* d_ws, size_t ws_size,
                              hipStream_t stream) {
    const float* inputs     = (const float*)d_in[0];
    const float* slots_init = (const float*)d_in[1];
    const float* mu         = (const float*)d_in[2];
    const float* logsig     = (const float*)d_in[3];
    const float* ln0w       = (const float*)d_in[4];
    const float* ln0b       = (const float*)d_in[5];
    const float* ln1w       = (const float*)d_in[6];
    const float* ln1b       = (const float*)d_in[7];
    const float* ln2w       = (const float*)d_in[8];
    const float* ln2b       = (const float*)d_in[9];
    const float* qW         = (const float*)d_in[10];
    const float* qb         = (const float*)d_in[11];
    const float* kW         = (const float*)d_in[12];
    const float* kb         = (const float*)d_in[13];
    const float* vW         = (const float*)d_in[14];
    const float* vb         = (const float*)d_in[15];
    const float* m1W        = (const float*)d_in[16];
    const float* m1b        = (const float*)d_in[17];
    const float* m2W        = (const float*)d_in[18];
    const float* m2b        = (const float*)d_in[19];

    char* ws = (char*)d_ws;
    ushort* xgs     = (ushort*)(ws);                   // 134,217,728 B
    float*  partials= (float*)(ws + 134217728);        //  16,777,216 B
    ushort* qkf     = (ushort*)(ws + 150994944);       //     524,288 B
    float*  slots   = (float*)(ws + 152567808);        //   1,048,576 B
    ushort* qWc     = (ushort*)(ws + 153616384);       //     393,216 B
    ushort* m1Wc    = (ushort*)(ws + 154009600);       //     786,432 B
    ushort* m2Wc    = (ushort*)(ws + 154796032);       //     786,432 B
    ushort* vWc     = (ushort*)(ws + 155582464);       //     393,216 B
    float*  denom   = (float*)(ws + 155975680);        //       4,096 B
    float*  qkb     = (float*)(ws + 155979776);        //       4,096 B
    float*  sums    = (float*)(ws + 155983872);        //         512 B (pad to 155,984,384)
    ushort* kWT     = (ushort*)(ws + 155984384);       //     393,216 B
    // total 156,377,600 B <= 157,295,104 B proven available

    kinit<<<1024, 256, 0, stream>>>(slots_init, mu, logsig, slots, sums);
    ktrans<<<336, 256, 0, stream>>>(qW, kW, m1W, m2W, vW, qWc, kWT, m1Wc, m2Wc, vWc);
    l0a<<<2048, 256, 0, stream>>>(inputs, sums);
    l0bs<<<1024, 256, 0, stream>>>(inputs, ln0w, ln0b, sums, xgs);
    kqm<<<64, 256, 0, stream>>>(slots, ln1w, ln1b, qWc, qb, kWT, kb, qkf, qkb, denom);

    for (int it = 0; it < 3; it++) {
        katt<<<1024, 256, 0, stream>>>(xgs, qkf, qkb, denom, partials);
        int nx = (it < 2) ? it + 1 : 2;
        ktail<<<64, 256, 0, stream>>>(partials, denom,
                                      vWc + it * 65536, vb + it * 256, ln2w, ln2b,
                                      m1Wc + it * 131072, m1b + it * 512,
                                      m2Wc + it * 131072, m2b + it * 256,
                                      (float*)d_out, it == 2 ? 1 : 0,
                                      ln1w, ln1b,
                                      qWc + nx * 65536, qb + nx * 256,
                                      kWT + nx * 65536, kb + nx * 256,
                                      qkf, qkb, denom, it < 2 ? 1 : 0);
    }
}

// Round 9
// 328.536 us; speedup vs baseline: 1.7618x; 1.1700x over previous
//
#include <hip/hip_runtime.h>
#include <hip/hip_bf16.h>

#define LN_EPS 1e-5f

typedef __attribute__((ext_vector_type(8))) short short8;   // 8 bf16
typedef __attribute__((ext_vector_type(4))) float f32x4;    // MFMA C/D frag

__device__ __forceinline__ ushort f2bf(float f) {
    __hip_bfloat16 h = __float2bfloat16(f);
    return *reinterpret_cast<ushort*>(&h);
}
__device__ __forceinline__ float bf2f(ushort u) {
    union { float f; unsigned int i; } c; c.i = ((unsigned int)u) << 16; return c.f;
}

// ---------------- init: slots0 = mu + exp(logsigma)*slots_init; zero LN0 sums --------
__global__ void kinit(const float* __restrict__ slots_init, const float* __restrict__ mu,
                      const float* __restrict__ logsig, float* __restrict__ slots,
                      float* __restrict__ sums) {
    int i = blockIdx.x * 256 + threadIdx.x;    // 262144 exactly
    int d = i & 255;
    slots[i] = mu[d] + __expf(logsig[d]) * slots_init[i];
    if (blockIdx.x == 0 && threadIdx.x < 128) sums[threadIdx.x] = 0.f;
}

// ---------------- weight prep --------------------------------------------------------
// Straight bf16 casts: qWc, vWc, m1Wc, m2Wc (B-frags read weight ROWS).
// Transpose: kWT[d][e] = kW[e][d].
__global__ void ktrans(const float* __restrict__ qW, const float* __restrict__ kW,
                       const float* __restrict__ m1W, const float* __restrict__ m2W,
                       const float* __restrict__ vW,
                       ushort* __restrict__ qWc, ushort* __restrict__ kWT,
                       ushort* __restrict__ m1Wc, ushort* __restrict__ m2Wc,
                       ushort* __restrict__ vWc) {
    int blk = blockIdx.x, t = threadIdx.x;
    int col = t & 63, rq = t >> 6;
    if (blk < 288) {   // straight 64x64-tile casts
        const float* src; ushort* dst; int C, tr, tc;
        if (blk < 48)        { int it = blk >> 4, rem = blk & 15; C = 256; tr = rem >> 2; tc = rem & 3;
                               src = qW + it * 65536;  dst = qWc + it * 65536; }
        else if (blk < 96)   { int li = blk - 48; int it = li >> 4, rem = li & 15; C = 256; tr = rem >> 2; tc = rem & 3;
                               src = vW + it * 65536;  dst = vWc + it * 65536; }
        else if (blk < 192)  { int li = blk - 96; int it = li >> 5, rem = li & 31; C = 256; tr = rem >> 2; tc = rem & 3;
                               src = m1W + it * 131072; dst = m1Wc + it * 131072; }
        else                 { int li = blk - 192; int it = li >> 5, rem = li & 31; C = 512; tr = rem >> 3; tc = rem & 7;
                               src = m2W + it * 131072; dst = m2Wc + it * 131072; }
        #pragma unroll
        for (int r = 0; r < 16; r++) {
            int row = r * 4 + rq;
            int idx = (tr * 64 + row) * C + tc * 64 + col;
            dst[idx] = f2bf(src[idx]);
        }
        return;
    }
    __shared__ float tile[64][65];
    int li = blk - 288; int it = li >> 4, rem = li & 15;
    int tr = rem >> 2, tc = rem & 3;
    const float* src = kW + it * 65536; ushort* dst = kWT + it * 65536;
    #pragma unroll
    for (int r = 0; r < 16; r++) {
        int row = r * 4 + rq;
        tile[row][col] = src[(tr * 64 + row) * 256 + tc * 64 + col];
    }
    __syncthreads();
    #pragma unroll
    for (int r = 0; r < 16; r++) {
        int row = r * 4 + rq;
        dst[(tc * 64 + row) * 256 + tr * 64 + col] = f2bf(tile[col][row]);
    }
}

// ---------------- LN0 pass 1 ---------------------------------------------------------
__global__ void l0a(const float* __restrict__ inp, float* __restrict__ sums) {
    int b = blockIdx.x >> 5, seg = blockIdx.x & 31;
    const float4* p = (const float4*)inp + (size_t)b * 262144 + seg * 8192 + threadIdx.x;
    float s = 0.f, sq = 0.f;
    #pragma unroll
    for (int k = 0; k < 32; k++) {
        float4 v = p[k * 256];
        s  += v.x + v.y + v.z + v.w;
        sq += v.x * v.x + v.y * v.y + v.z * v.z + v.w * v.w;
    }
    __shared__ float r1[256], r2[256];
    r1[threadIdx.x] = s; r2[threadIdx.x] = sq; __syncthreads();
    for (int st = 128; st > 0; st >>= 1) {
        if (threadIdx.x < st) { r1[threadIdx.x] += r1[threadIdx.x + st]; r2[threadIdx.x] += r2[threadIdx.x + st]; }
        __syncthreads();
    }
    if (threadIdx.x == 0) { atomicAdd(&sums[b], r1[0]); atomicAdd(&sums[64 + b], r2[0]); }
}

// ---------------- LN0 pass 2: normalize + write bf16 x in MFMA-frag order ------------
__global__ void l0bs(const float* __restrict__ inp, const float* __restrict__ ln0w,
                     const float* __restrict__ ln0b, const float* __restrict__ sums,
                     ushort* __restrict__ xgs) {
    int gw = blockIdx.x * 4 + (threadIdx.x >> 6);     // 4096 wave tasks
    int lane = threadIdx.x & 63, l15 = lane & 15, quad = lane >> 4;
    int ntile = gw >> 4;
    int ds = (gw >> 1) & 7;
    int b0 = (gw & 1) * 32;
    int n = ntile * 16 + l15;
    int dcol = ds * 32 + quad * 8;
    const float4* wp = (const float4*)(ln0w + n * 256 + dcol);
    const float4* bp = (const float4*)(ln0b + n * 256 + dcol);
    float4 w0 = wp[0], w1 = wp[1];
    float4 c0 = bp[0], c1 = bp[1];
    #pragma unroll 4
    for (int bi = 0; bi < 32; bi++) {
        int b = b0 + bi;
        float mean = sums[b] * (1.f / 1048576.f);
        float rstd = rsqrtf(sums[64 + b] * (1.f / 1048576.f) - mean * mean + LN_EPS);
        const float4* xp = (const float4*)(inp + (size_t)b * 1048576 + n * 256 + dcol);
        float4 v0 = xp[0], v1 = xp[1];
        ushort o[8];
        o[0] = f2bf((v0.x - mean) * rstd * w0.x + c0.x);
        o[1] = f2bf((v0.y - mean) * rstd * w0.y + c0.y);
        o[2] = f2bf((v0.z - mean) * rstd * w0.z + c0.z);
        o[3] = f2bf((v0.w - mean) * rstd * w0.w + c0.w);
        o[4] = f2bf((v1.x - mean) * rstd * w1.x + c1.x);
        o[5] = f2bf((v1.y - mean) * rstd * w1.y + c1.y);
        o[6] = f2bf((v1.z - mean) * rstd * w1.z + c1.z);
        o[7] = f2bf((v1.w - mean) * rstd * w1.w + c1.w);
        *(short8*)(xgs + ((size_t)((b * 256 + ntile) * 8 + ds) * 64 + lane) * 8) = *(short8*)o;
    }
}

// ---------------- q-gen core (shared by kqm and ktail P6), 1024 threads / 16 waves ---
// Inputs: slbq (LN1'd slots bf16, pitch 264) already in LDS + barrier'd.
// Outputs: qkf/qkb/denom_out. Uses qsf/qsb/qkl scratch.
__device__ __forceinline__ void qgen_core(
        int b, int t, int lane, int w, int l15, int quad,
        ushort* slbq, float* qsf, ushort* qsb, ushort* qkl,
        const ushort* __restrict__ qWc, const float* __restrict__ qb,
        const ushort* __restrict__ kWT, const float* __restrict__ kb,
        ushort* __restrict__ qkf, float* __restrict__ qkb,
        float* __restrict__ denom_out) {
    // pass1: q'[s,e] = (sum_d sl[s,d]*qW[e,d] + qb[e]) / 16 ; wave w -> e-tile w
    {
        short8 aq[8];
        #pragma unroll
        for (int ds = 0; ds < 8; ds++)
            aq[ds] = *(const short8*)(&slbq[l15 * 264 + ds * 32 + quad * 8]);
        int et = w;
        f32x4 c = f32x4{0.f, 0.f, 0.f, 0.f};
        #pragma unroll
        for (int ds = 0; ds < 8; ds++) {
            short8 bf_ = *(const short8*)(qWc + (size_t)(et * 16 + l15) * 256 + ds * 32 + quad * 8);
            c = __builtin_amdgcn_mfma_f32_16x16x32_bf16(aq[ds], bf_, c, 0, 0, 0);
        }
        float qbv = qb[et * 16 + l15];
        #pragma unroll
        for (int r = 0; r < 4; r++) {
            float val = (c[r] + qbv) * (1.f / 16.f);
            qsf[(quad * 4 + r) * 260 + et * 16 + l15] = val;
            qsb[(quad * 4 + r) * 264 + et * 16 + l15] = f2bf(val);
        }
    }
    __syncthreads();
    // qkb[s=w] via lanes l15<16 of wave w (quad 0 writes)
    {
        float pp = 0.f;
        #pragma unroll
        for (int e = 0; e < 16; e++) pp += qsf[w * 260 + l15 * 16 + e] * kb[l15 * 16 + e];
        pp += __shfl_xor(pp, 1); pp += __shfl_xor(pp, 2);
        pp += __shfl_xor(pp, 4); pp += __shfl_xor(pp, 8);
        if (lane == 0) qkb[b * 16 + w] = pp;
    }
    if (t < 16) denom_out[b * 16 + t] = 0.f;
    // pass2: qk[s,d] = sum_e q'[s,e]*kW[e,d] ; wave w -> d-tile w
    {
        short8 aq2[8];
        #pragma unroll
        for (int es = 0; es < 8; es++)
            aq2[es] = *(const short8*)(&qsb[l15 * 264 + es * 32 + quad * 8]);
        int dt = w;
        f32x4 c2 = f32x4{0.f, 0.f, 0.f, 0.f};
        #pragma unroll
        for (int es = 0; es < 8; es++) {
            short8 bf2 = *(const short8*)(kWT + (size_t)(dt * 16 + l15) * 256 + es * 32 + quad * 8);
            c2 = __builtin_amdgcn_mfma_f32_16x16x32_bf16(aq2[es], bf2, c2, 0, 0, 0);
        }
        #pragma unroll
        for (int r = 0; r < 4; r++)
            qkl[(quad * 4 + r) * 264 + dt * 16 + l15] = f2bf(c2[r]);
    }
    __syncthreads();
    // qkf store: waves 0..7, ds = w
    if (w < 8) {
        short8 v = *(const short8*)(&qkl[l15 * 264 + w * 32 + quad * 8]);
        *(short8*)(qkf + (size_t)(b * 8 + w) * 512 + lane * 8) = v;
    }
}

// ---------------- initial q-gen (it=0): 1024 threads ---------------------------------
__global__ void kqm(const float* __restrict__ slots, const float* __restrict__ ln1w,
                    const float* __restrict__ ln1b, const ushort* __restrict__ qWc,
                    const float* __restrict__ qb, const ushort* __restrict__ kWT,
                    const float* __restrict__ kb,
                    ushort* __restrict__ qkf, float* __restrict__ qkb,
                    float* __restrict__ denom) {
    int b = blockIdx.x, t = threadIdx.x;
    int lane = t & 63, w = t >> 6, l15 = lane & 15, quad = lane >> 4;
    __shared__ ushort slbq[16 * 264];
    __shared__ ushort qsb[16 * 264];
    __shared__ ushort qkl[16 * 264];
    __shared__ float  qsf[16 * 260];
    __shared__ float  wr1[16], wr2[16];

    int g = t >> 8, c = t & 255;
    float vals[4]; float s = 0.f, sq = 0.f;
    #pragma unroll
    for (int kk = 0; kk < 4; kk++) {
        float v = slots[b * 4096 + (g * 4 + kk) * 256 + c];
        vals[kk] = v; s += v; sq += v * v;
    }
    #pragma unroll
    for (int m = 1; m < 64; m <<= 1) { s += __shfl_xor(s, m); sq += __shfl_xor(sq, m); }
    if (lane == 0) { wr1[w] = s; wr2[w] = sq; }
    __syncthreads();
    float ts = 0.f, tsq = 0.f;
    #pragma unroll
    for (int i = 0; i < 16; i++) { ts += wr1[i]; tsq += wr2[i]; }
    float m_  = ts * (1.f / 4096.f);
    float rs_ = rsqrtf(tsq * (1.f / 4096.f) - m_ * m_ + LN_EPS);
    #pragma unroll
    for (int kk = 0; kk < 4; kk++) {
        int k = g * 4 + kk;
        slbq[k * 264 + c] = f2bf((vals[kk] - m_) * rs_ * ln1w[k * 256 + c] + ln1b[k * 256 + c]);
    }
    __syncthreads();
    qgen_core(b, t, lane, w, l15, quad, slbq, qsf, qsb, qkl,
              qWc, qb, kWT, kb, qkf, qkb, denom);
}

// ---------------- THE hot kernel (unchanged from R8) ---------------------------------
__launch_bounds__(256, 4)
__global__ void katt(const ushort* __restrict__ xgs, const ushort* __restrict__ qkf,
                     const float* __restrict__ qkb, float* __restrict__ denom,
                     float* __restrict__ partials) {
    int b = blockIdx.x >> 4, chunk = blockIdx.x & 15;
    int tid = threadIdx.x;
    int lane = tid & 63, w = tid >> 6;
    int l15 = lane & 15, quad = lane >> 4;

    __shared__ ushort xtT[16384];       // x^T in ax-B-frag order (32 KB)
    __shared__ ushort attn[16 * 72];    // attn [s][n_local], pitch 72

    short8 ilo, ihi;
    #pragma unroll
    for (int j = 0; j < 8; j++) {
        ilo[j] = (short)((quad * 8 + j == l15)      ? 0x3F80 : 0);
        ihi[j] = (short)((quad * 8 + j == l15 + 16) ? 0x3F80 : 0);
    }
    int wbase = (w >> 1) * 512 + ((w * 2 + (quad >> 1)) & 3) * 128 + l15 * 8 + (quad & 1) * 4;

    short8 qkfr[8];
    #pragma unroll
    for (int ds = 0; ds < 8; ds++)
        qkfr[ds] = *(const short8*)(qkf + ((size_t)(b * 8 + ds) * 512 + lane * 8));
    float4 qo = *(const float4*)(qkb + b * 16 + quad * 4);

    f32x4 pacc[4];
    #pragma unroll
    for (int u = 0; u < 4; u++) pacc[u] = f32x4{0.f, 0.f, 0.f, 0.f};
    float dp0 = 0.f, dp1 = 0.f, dp2 = 0.f, dp3 = 0.f;

    int tile0 = b * 256 + chunk * 16;

    short8 pf[8];
    #pragma unroll
    for (int i = 0; i < 8; i++)
        pf[i] = *(const short8*)(xgs + (((size_t)(tile0 + w) * 8 + i) * 64 + lane) * 8);

    #pragma unroll 1
    for (int sub = 0; sub < 4; sub++) {
        __syncthreads();
        f32x4 dc = f32x4{0.f, 0.f, 0.f, 0.f};
        #pragma unroll
        for (int ds = 0; ds < 8; ds++)
            dc = __builtin_amdgcn_mfma_f32_16x16x32_bf16(qkfr[ds], pf[ds], dc, 0, 0, 0);
        dc[0] += qo.x; dc[1] += qo.y; dc[2] += qo.z; dc[3] += qo.w;
        float mx = fmaxf(fmaxf(dc[0], dc[1]), fmaxf(dc[2], dc[3]));
        mx = fmaxf(mx, __shfl_xor(mx, 16));
        mx = fmaxf(mx, __shfl_xor(mx, 32));
        float e0 = __expf(dc[0] - mx), e1 = __expf(dc[1] - mx);
        float e2 = __expf(dc[2] - mx), e3 = __expf(dc[3] - mx);
        float lsum = e0 + e1 + e2 + e3;
        lsum += __shfl_xor(lsum, 16); lsum += __shfl_xor(lsum, 32);
        float inv = 1.f / lsum;
        float p0 = e0 * inv, p1 = e1 * inv, p2 = e2 * inv, p3 = e3 * inv;
        dp0 += p0; dp1 += p1; dp2 += p2; dp3 += p3;
        attn[(quad * 4 + 0) * 72 + w * 16 + l15] = f2bf(p0);
        attn[(quad * 4 + 1) * 72 + w * 16 + l15] = f2bf(p1);
        attn[(quad * 4 + 2) * 72 + w * 16 + l15] = f2bf(p2);
        attn[(quad * 4 + 3) * 72 + w * 16 + l15] = f2bf(p3);
        f32x4 zz = f32x4{0.f, 0.f, 0.f, 0.f};
        #pragma unroll
        for (int ds = 0; ds < 8; ds++) {
            f32x4 tlo = __builtin_amdgcn_mfma_f32_16x16x32_bf16(pf[ds], ilo, zz, 0, 0, 0);
            f32x4 thi = __builtin_amdgcn_mfma_f32_16x16x32_bf16(pf[ds], ihi, zz, 0, 0, 0);
            unsigned lo0 = (__float_as_uint(tlo[0]) >> 16) | (__float_as_uint(tlo[1]) & 0xFFFF0000u);
            unsigned lo1 = (__float_as_uint(tlo[2]) >> 16) | (__float_as_uint(tlo[3]) & 0xFFFF0000u);
            unsigned hi0 = (__float_as_uint(thi[0]) >> 16) | (__float_as_uint(thi[1]) & 0xFFFF0000u);
            unsigned hi1 = (__float_as_uint(thi[2]) >> 16) | (__float_as_uint(thi[3]) & 0xFFFF0000u);
            *(uint2*)(&xtT[(ds * 2 + 0) * 1024 + wbase]) = make_uint2(lo0, lo1);
            *(uint2*)(&xtT[(ds * 2 + 1) * 1024 + wbase]) = make_uint2(hi0, hi1);
        }
        if (sub < 3) {
            #pragma unroll
            for (int i = 0; i < 8; i++)
                pf[i] = *(const short8*)(xgs + (((size_t)(tile0 + (sub + 1) * 4 + w) * 8 + i) * 64 + lane) * 8);
        }
        __syncthreads();

        #pragma unroll
        for (int ns = 0; ns < 2; ns++) {
            short8 aa = *(const short8*)(&attn[l15 * 72 + ns * 32 + quad * 8]);
            #pragma unroll
            for (int u = 0; u < 4; u++) {
                short8 bb = *(const short8*)(&xtT[((w * 4 + u) * 2 + ns) * 512 + lane * 8]);
                pacc[u] = __builtin_amdgcn_mfma_f32_16x16x32_bf16(aa, bb, pacc[u], 0, 0, 0);
            }
        }
    }

    #pragma unroll
    for (int m = 1; m < 16; m <<= 1) {
        dp0 += __shfl_xor(dp0, m); dp1 += __shfl_xor(dp1, m);
        dp2 += __shfl_xor(dp2, m); dp3 += __shfl_xor(dp3, m);
    }
    if (l15 == 0) {
        atomicAdd(&denom[b * 16 + quad * 4 + 0], dp0);
        atomicAdd(&denom[b * 16 + quad * 4 + 1], dp1);
        atomicAdd(&denom[b * 16 + quad * 4 + 2], dp2);
        atomicAdd(&denom[b * 16 + quad * 4 + 3], dp3);
    }

    float* pout = partials + (size_t)(b * 16 + chunk) * 4096;   // [s][d]
    #pragma unroll
    for (int u = 0; u < 4; u++)
        #pragma unroll
        for (int r = 0; r < 4; r++)
            pout[(quad * 4 + r) * 256 + (w * 4 + u) * 16 + l15] = pacc[u][r];
}

// ---------------- fused tail, now 1024 threads / 16 waves ----------------------------
// partials-reduce -> v-apply -> LN2 -> MLP1 -> MLP2+res -> (optional) next q-gen.
// grid 64 (one block per batch). Same LDS pool aliasing/liveness as R8 (proven).
__global__ void ktail(const float* __restrict__ partials, const float* __restrict__ denom,
                      const ushort* __restrict__ vWc, const float* __restrict__ vb,
                      const float* __restrict__ ln2w, const float* __restrict__ ln2b,
                      const ushort* __restrict__ m1Wc, const float* __restrict__ m1b,
                      const ushort* __restrict__ m2Wc, const float* __restrict__ m2b,
                      float* __restrict__ final_out, int write_final,
                      const float* __restrict__ ln1w, const float* __restrict__ ln1b,
                      const ushort* __restrict__ qWc_n, const float* __restrict__ qb_n,
                      const ushort* __restrict__ kWT_n, const float* __restrict__ kb_n,
                      ushort* __restrict__ qkf, float* __restrict__ qkb,
                      float* __restrict__ denom_out, int gen) {
    int b = blockIdx.x, t = threadIdx.x;
    int lane = t & 63, w = t >> 6, l15 = lane & 15, quad = lane >> 4;

    __shared__ char pool[60416];
    __shared__ float dnb[16];
    __shared__ float wr1[16], wr2[16];
    ushort* axsb = (ushort*)pool;                  // [0,8448)      P1-2: ax bf16 [16][264]
    ushort* s2b  = (ushort*)(pool + 8448);         // [8448,16896)  P2-4: LN2'd slots bf16
    float*  slt  = (float*)(pool + 16896);         // [16896,33280) P2-5: v-apply out f32 [16][256]
    ushort* hlb  = (ushort*)(pool + 35328);        // [35328,51968) P4-5: relu(h) bf16 [16][520]
    // P6 aliases (regions dead by then):
    float*  slt2 = (float*)pool;                   // [0,16384)     new slots f32
    ushort* slbq = (ushort*)(pool + 16896);        // [16896,25344) LN1'd slots bf16
    ushort* qkl  = (ushort*)(pool + 16896);        // reuse after slbq A-frags loaded
    float*  qsf  = (float*)(pool + 35328);         // [35328,51968) q' f32 [16][260]
    ushort* qsb  = (ushort*)(pool + 51968);        // [51968,60416) q' bf16 [16][264]

    // ---- P1: reduce partials chunks -> axsb (bf16, A-frag pitch); 4 outputs/thread --
    const float* pp = partials + (size_t)b * 65536;
    #pragma unroll
    for (int i = 0; i < 4; i++) {
        int idx = i * 1024 + t;                 // s = idx>>8, d = idx&255
        float ss = 0.f;
        #pragma unroll
        for (int c = 0; c < 16; c++) ss += pp[c * 4096 + idx];
        axsb[(idx >> 8) * 264 + (idx & 255)] = f2bf(ss);
    }
    if (t < 16) dnb[t] = denom[b * 16 + t];
    __syncthreads();

    // ---- P2: v-apply (MFMA); wave w -> e-tile w. slots_mid + LN2 stats --------------
    float myv[4];
    {
        short8 af[8];
        #pragma unroll
        for (int ds = 0; ds < 8; ds++)
            af[ds] = *(const short8*)(&axsb[l15 * 264 + ds * 32 + quad * 8]);
        int et = w;
        f32x4 c = f32x4{0.f, 0.f, 0.f, 0.f};
        #pragma unroll
        for (int ds = 0; ds < 8; ds++) {
            short8 bf_ = *(const short8*)(vWc + (size_t)(et * 16 + l15) * 256 + ds * 32 + quad * 8);
            c = __builtin_amdgcn_mfma_f32_16x16x32_bf16(af[ds], bf_, c, 0, 0, 0);
        }
        float vbe = vb[et * 16 + l15];
        #pragma unroll
        for (int r = 0; r < 4; r++) {
            float A = dnb[quad * 4 + r];
            float val = (c[r] + vbe * A) / (A + 1e-7f);
            slt[(quad * 4 + r) * 256 + et * 16 + l15] = val;
            myv[r] = val;
        }
    }
    {   // LN2 stats: each (s,e) counted once across (w,quad,l15,r)
        float s = myv[0] + myv[1] + myv[2] + myv[3];
        float sq = myv[0]*myv[0] + myv[1]*myv[1] + myv[2]*myv[2] + myv[3]*myv[3];
        #pragma unroll
        for (int m = 1; m < 64; m <<= 1) { s += __shfl_xor(s, m); sq += __shfl_xor(sq, m); }
        if (lane == 0) { wr1[w] = s; wr2[w] = sq; }
        __syncthreads();
    }
    float ts = 0.f, tsq = 0.f;
    #pragma unroll
    for (int i = 0; i < 16; i++) { ts += wr1[i]; tsq += wr2[i]; }
    float m2_ = ts * (1.f / 4096.f);
    float rs2 = rsqrtf(tsq * (1.f / 4096.f) - m2_ * m2_ + LN_EPS);
    {
        int e = w * 16 + l15;
        #pragma unroll
        for (int r = 0; r < 4; r++) {
            int ss_ = quad * 4 + r;
            s2b[ss_ * 264 + e] = f2bf((myv[r] - m2_) * rs2 * ln2w[ss_ * 256 + e] + ln2b[ss_ * 256 + e]);
        }
    }
    __syncthreads();

    // ---- P4: MLP1 (MFMA); wave w -> j-tiles {w, w+16} -------------------------------
    {
        short8 a2[8];
        #pragma unroll
        for (int ds = 0; ds < 8; ds++)
            a2[ds] = *(const short8*)(&s2b[l15 * 264 + ds * 32 + quad * 8]);
        #pragma unroll
        for (int p = 0; p < 2; p++) {
            int jt = w + p * 16;
            f32x4 c = f32x4{0.f, 0.f, 0.f, 0.f};
            #pragma unroll
            for (int ds = 0; ds < 8; ds++) {
                short8 bf_ = *(const short8*)(m1Wc + (size_t)(jt * 16 + l15) * 256 + ds * 32 + quad * 8);
                c = __builtin_amdgcn_mfma_f32_16x16x32_bf16(a2[ds], bf_, c, 0, 0, 0);
            }
            float bias = m1b[jt * 16 + l15];
            #pragma unroll
            for (int r = 0; r < 4; r++)
                hlb[(quad * 4 + r) * 520 + jt * 16 + l15] = f2bf(fmaxf(c[r] + bias, 0.f));
        }
    }
    __syncthreads();

    // ---- P5: MLP2 (MFMA) + residual; wave w -> d-tile w -----------------------------
    {
        short8 a3[16];
        #pragma unroll
        for (int js = 0; js < 16; js++)
            a3[js] = *(const short8*)(&hlb[l15 * 520 + js * 32 + quad * 8]);
        int dt = w;
        f32x4 c = f32x4{0.f, 0.f, 0.f, 0.f};
        #pragma unroll
        for (int js = 0; js < 16; js++) {
            short8 bf_ = *(const short8*)(m2Wc + (size_t)(dt * 16 + l15) * 512 + js * 32 + quad * 8);
            c = __builtin_amdgcn_mfma_f32_16x16x32_bf16(a3[js], bf_, c, 0, 0, 0);
        }
        float b2 = m2b[dt * 16 + l15];
        #pragma unroll
        for (int r = 0; r < 4; r++) {
            int ss_ = quad * 4 + r, d = dt * 16 + l15;
            float val = slt[ss_ * 256 + d] + c[r] + b2;
            slt2[ss_ * 256 + d] = val;
            if (write_final) final_out[(size_t)b * 4096 + ss_ * 256 + d] = val;
        }
    }
    __syncthreads();

    // ---- P6: next-iter q-gen (slots from LDS) ---------------------------------------
    if (gen) {
        int g = t >> 8, cc = t & 255;
        float vals[4]; float s = 0.f, sq = 0.f;
        #pragma unroll
        for (int kk = 0; kk < 4; kk++) {
            float v = slt2[(g * 4 + kk) * 256 + cc];
            vals[kk] = v; s += v; sq += v * v;
        }
        #pragma unroll
        for (int m = 1; m < 64; m <<= 1) { s += __shfl_xor(s, m); sq += __shfl_xor(sq, m); }
        if (lane == 0) { wr1[w] = s; wr2[w] = sq; }
        __syncthreads();
        float ts1 = 0.f, tsq1 = 0.f;
        #pragma unroll
        for (int i = 0; i < 16; i++) { ts1 += wr1[i]; tsq1 += wr2[i]; }
        float m1_ = ts1 * (1.f / 4096.f);
        float rs1 = rsqrtf(tsq1 * (1.f / 4096.f) - m1_ * m1_ + LN_EPS);
        #pragma unroll
        for (int kk = 0; kk < 4; kk++) {
            int k = g * 4 + kk;
            slbq[k * 264 + cc] = f2bf((vals[kk] - m1_) * rs1 * ln1w[k * 256 + cc] + ln1b[k * 256 + cc]);
        }
        __syncthreads();
        qgen_core(b, t, lane, w, l15, quad, slbq, qsf, qsb, qkl,
                  qWc_n, qb_n, kWT_n, kb_n, qkf, qkb, denom_out);
    }
}

extern "C" void kernel_launch(void* const* d_in, const int* in_sizes, int n_in,
                              void* d_out, int out_size, void* d_ws, size_t ws_size,
                              hipStream_t stream) {
    const float* inputs     = (const float*)d_in[0];
    const float* slots_init = (const float*)d_in[1];
    const float* mu         = (const float*)d_in[2];
    const float* logsig     = (const float*)d_in[3];
    const float* ln0w       = (const float*)d_in[4];
    const float* ln0b       = (const float*)d_in[5];
    const float* ln1w       = (const float*)d_in[6];
    const float* ln1b       = (const float*)d_in[7];
    const float* ln2w       = (const float*)d_in[8];
    const float* ln2b       = (const float*)d_in[9];
    const float* qW         = (const float*)d_in[10];
    const float* qb         = (const float*)d_in[11];
    const float* kW         = (const float*)d_in[12];
    const float* kb         = (const float*)d_in[13];
    const float* vW         = (const float*)d_in[14];
    const float* vb         = (const float*)d_in[15];
    const float* m1W        = (const float*)d_in[16];
    const float* m1b        = (const float*)d_in[17];
    const float* m2W        = (const float*)d_in[18];
    const float* m2b        = (const float*)d_in[19];

    char* ws = (char*)d_ws;
    ushort* xgs     = (ushort*)(ws);                   // 134,217,728 B
    float*  partials= (float*)(ws + 134217728);        //  16,777,216 B
    ushort* qkf     = (ushort*)(ws + 150994944);       //     524,288 B
    float*  slots   = (float*)(ws + 152567808);        //   1,048,576 B
    ushort* qWc     = (ushort*)(ws + 153616384);       //     393,216 B
    ushort* m1Wc    = (ushort*)(ws + 154009600);       //     786,432 B
    ushort* m2Wc    = (ushort*)(ws + 154796032);       //     786,432 B
    ushort* vWc     = (ushort*)(ws + 155582464);       //     393,216 B
    float*  denom   = (float*)(ws + 155975680);        //       4,096 B
    float*  qkb     = (float*)(ws + 155979776);        //       4,096 B
    float*  sums    = (float*)(ws + 155983872);        //         512 B (pad to 155,984,384)
    ushort* kWT     = (ushort*)(ws + 155984384);       //     393,216 B
    // total 156,377,600 B <= 157,295,104 B proven available

    kinit<<<1024, 256, 0, stream>>>(slots_init, mu, logsig, slots, sums);
    ktrans<<<336, 256, 0, stream>>>(qW, kW, m1W, m2W, vW, qWc, kWT, m1Wc, m2Wc, vWc);
    l0a<<<2048, 256, 0, stream>>>(inputs, sums);
    l0bs<<<1024, 256, 0, stream>>>(inputs, ln0w, ln0b, sums, xgs);
    kqm<<<64, 1024, 0, stream>>>(slots, ln1w, ln1b, qWc, qb, kWT, kb, qkf, qkb, denom);

    for (int it = 0; it < 3; it++) {
        katt<<<1024, 256, 0, stream>>>(xgs, qkf, qkb, denom, partials);
        int nx = (it < 2) ? it + 1 : 2;
        ktail<<<64, 1024, 0, stream>>>(partials, denom,
                                       vWc + it * 65536, vb + it * 256, ln2w, ln2b,
                                       m1Wc + it * 131072, m1b + it * 512,
                                       m2Wc + it * 131072, m2b + it * 256,
                                       (float*)d_out, it == 2 ? 1 : 0,
                                       ln1w, ln1b,
                                       qWc + nx * 65536, qb + nx * 256,
                                       kWT + nx * 65536, kb + nx * 256,
                                       qkf, qkb, denom, it < 2 ? 1 : 0);
    }
}

// Round 10
// 316.549 us; speedup vs baseline: 1.8286x; 1.0379x over previous
//
#include <hip/hip_runtime.h>
#include <hip/hip_bf16.h>

#define LN_EPS 1e-5f

typedef __attribute__((ext_vector_type(8))) short short8;   // 8 bf16
typedef __attribute__((ext_vector_type(4))) float f32x4;    // MFMA C/D frag

__device__ __forceinline__ ushort f2bf(float f) {
    __hip_bfloat16 h = __float2bfloat16(f);
    return *reinterpret_cast<ushort*>(&h);
}
__device__ __forceinline__ float bf2f(ushort u) {
    union { float f; unsigned int i; } c; c.i = ((unsigned int)u) << 16; return c.f;
}

// ---------------- kprep: weight prep (blk 0-335) + LN0 pass 1 (blk 336-2383) ---------
// Weight prep: straight bf16 casts qWc,vWc,m1Wc,m2Wc; transpose kWT[d][e]=kW[e][d].
__global__ void kprep(const float* __restrict__ qW, const float* __restrict__ kW,
                      const float* __restrict__ m1W, const float* __restrict__ m2W,
                      const float* __restrict__ vW,
                      ushort* __restrict__ qWc, ushort* __restrict__ kWT,
                      ushort* __restrict__ m1Wc, ushort* __restrict__ m2Wc,
                      ushort* __restrict__ vWc,
                      const float* __restrict__ inp, float* __restrict__ sums) {
    __shared__ float tile[64][65];
    __shared__ float r1[256], r2[256];
    int blk = blockIdx.x, t = threadIdx.x;
    if (blk < 288) {   // straight 64x64-tile casts
        int col = t & 63, rq = t >> 6;
        const float* src; ushort* dst; int C, tr, tc;
        if (blk < 48)        { int it = blk >> 4, rem = blk & 15; C = 256; tr = rem >> 2; tc = rem & 3;
                               src = qW + it * 65536;  dst = qWc + it * 65536; }
        else if (blk < 96)   { int li = blk - 48; int it = li >> 4, rem = li & 15; C = 256; tr = rem >> 2; tc = rem & 3;
                               src = vW + it * 65536;  dst = vWc + it * 65536; }
        else if (blk < 192)  { int li = blk - 96; int it = li >> 5, rem = li & 31; C = 256; tr = rem >> 2; tc = rem & 3;
                               src = m1W + it * 131072; dst = m1Wc + it * 131072; }
        else                 { int li = blk - 192; int it = li >> 5, rem = li & 31; C = 512; tr = rem >> 3; tc = rem & 7;
                               src = m2W + it * 131072; dst = m2Wc + it * 131072; }
        #pragma unroll
        for (int r = 0; r < 16; r++) {
            int row = r * 4 + rq;
            int idx = (tr * 64 + row) * C + tc * 64 + col;
            dst[idx] = f2bf(src[idx]);
        }
        return;
    }
    if (blk < 336) {   // kWT transpose
        int col = t & 63, rq = t >> 6;
        int li = blk - 288; int it = li >> 4, rem = li & 15;
        int tr = rem >> 2, tc = rem & 3;
        const float* src = kW + it * 65536; ushort* dst = kWT + it * 65536;
        #pragma unroll
        for (int r = 0; r < 16; r++) {
            int row = r * 4 + rq;
            tile[row][col] = src[(tr * 64 + row) * 256 + tc * 64 + col];
        }
        __syncthreads();
        #pragma unroll
        for (int r = 0; r < 16; r++) {
            int row = r * 4 + rq;
            dst[(tc * 64 + row) * 256 + tr * 64 + col] = f2bf(tile[col][row]);
        }
        return;
    }
    // ---- LN0 pass 1 ----
    int lb = blk - 336;
    int b = lb >> 5, seg = lb & 31;
    const float4* p = (const float4*)inp + (size_t)b * 262144 + seg * 8192 + t;
    float s = 0.f, sq = 0.f;
    #pragma unroll
    for (int k = 0; k < 32; k++) {
        float4 v = p[k * 256];
        s  += v.x + v.y + v.z + v.w;
        sq += v.x * v.x + v.y * v.y + v.z * v.z + v.w * v.w;
    }
    r1[t] = s; r2[t] = sq; __syncthreads();
    for (int st = 128; st > 0; st >>= 1) {
        if (t < st) { r1[t] += r1[t + st]; r2[t] += r2[t + st]; }
        __syncthreads();
    }
    if (t == 0) { atomicAdd(&sums[b], r1[0]); atomicAdd(&sums[64 + b], r2[0]); }
}

// ---------------- q-gen core (shared), 1024 threads / 16 waves ----------------------
__device__ __forceinline__ void qgen_core(
        int b, int t, int lane, int w, int l15, int quad,
        ushort* slbq, float* qsf, ushort* qsb, ushort* qkl,
        const ushort* __restrict__ qWc, const float* __restrict__ qb,
        const ushort* __restrict__ kWT, const float* __restrict__ kb,
        ushort* __restrict__ qkf, float* __restrict__ qkb,
        float* __restrict__ denom_out) {
    // pass1: q'[s,e] = (sum_d sl[s,d]*qW[e,d] + qb[e]) / 16 ; wave w -> e-tile w
    {
        short8 aq[8];
        #pragma unroll
        for (int ds = 0; ds < 8; ds++)
            aq[ds] = *(const short8*)(&slbq[l15 * 264 + ds * 32 + quad * 8]);
        int et = w;
        f32x4 c = f32x4{0.f, 0.f, 0.f, 0.f};
        #pragma unroll
        for (int ds = 0; ds < 8; ds++) {
            short8 bf_ = *(const short8*)(qWc + (size_t)(et * 16 + l15) * 256 + ds * 32 + quad * 8);
            c = __builtin_amdgcn_mfma_f32_16x16x32_bf16(aq[ds], bf_, c, 0, 0, 0);
        }
        float qbv = qb[et * 16 + l15];
        #pragma unroll
        for (int r = 0; r < 4; r++) {
            float val = (c[r] + qbv) * (1.f / 16.f);
            qsf[(quad * 4 + r) * 260 + et * 16 + l15] = val;
            qsb[(quad * 4 + r) * 264 + et * 16 + l15] = f2bf(val);
        }
    }
    __syncthreads();
    // qkb[s=w]
    {
        float pp = 0.f;
        #pragma unroll
        for (int e = 0; e < 16; e++) pp += qsf[w * 260 + l15 * 16 + e] * kb[l15 * 16 + e];
        pp += __shfl_xor(pp, 1); pp += __shfl_xor(pp, 2);
        pp += __shfl_xor(pp, 4); pp += __shfl_xor(pp, 8);
        if (lane == 0) qkb[b * 16 + w] = pp;
    }
    if (t < 16) denom_out[b * 16 + t] = 0.f;
    // pass2: qk[s,d] = sum_e q'[s,e]*kW[e,d] ; wave w -> d-tile w
    {
        short8 aq2[8];
        #pragma unroll
        for (int es = 0; es < 8; es++)
            aq2[es] = *(const short8*)(&qsb[l15 * 264 + es * 32 + quad * 8]);
        int dt = w;
        f32x4 c2 = f32x4{0.f, 0.f, 0.f, 0.f};
        #pragma unroll
        for (int es = 0; es < 8; es++) {
            short8 bf2 = *(const short8*)(kWT + (size_t)(dt * 16 + l15) * 256 + es * 32 + quad * 8);
            c2 = __builtin_amdgcn_mfma_f32_16x16x32_bf16(aq2[es], bf2, c2, 0, 0, 0);
        }
        #pragma unroll
        for (int r = 0; r < 4; r++)
            qkl[(quad * 4 + r) * 264 + dt * 16 + l15] = f2bf(c2[r]);
    }
    __syncthreads();
    if (w < 8) {
        short8 v = *(const short8*)(&qkl[l15 * 264 + w * 32 + quad * 8]);
        *(short8*)(qkf + (size_t)(b * 8 + w) * 512 + lane * 8) = v;
    }
}

// ---------------- lkq: LN0 pass 2 (blk 0-255, 16 waves each) + initial q-gen (256-319)
// l0bs wave task map bijective with R9 (gw = blk*16 + wid). kqm part computes
// slots0 = mu + exp(logsigma)*slots_init inline (identical values to old kinit).
__global__ void lkq(const float* __restrict__ inp, const float* __restrict__ ln0w,
                    const float* __restrict__ ln0b, const float* __restrict__ sums,
                    ushort* __restrict__ xgs,
                    const float* __restrict__ slots_init, const float* __restrict__ mu,
                    const float* __restrict__ logsig,
                    const float* __restrict__ ln1w, const float* __restrict__ ln1b,
                    const ushort* __restrict__ qWc, const float* __restrict__ qb,
                    const ushort* __restrict__ kWT, const float* __restrict__ kb,
                    ushort* __restrict__ qkf, float* __restrict__ qkb,
                    float* __restrict__ denom) {
    __shared__ ushort slbq[16 * 264];
    __shared__ ushort qsb[16 * 264];
    __shared__ ushort qkl[16 * 264];
    __shared__ float  qsf[16 * 260];
    __shared__ float  wr1[16], wr2[16];
    int t = threadIdx.x;
    int lane = t & 63, w = t >> 6, l15 = lane & 15, quad = lane >> 4;

    if (blockIdx.x < 256) {
        // ---- LN0 pass 2 ----
        int gw = blockIdx.x * 16 + w;                 // 4096 wave tasks
        int ntile = gw >> 4;
        int ds = (gw >> 1) & 7;
        int b0 = (gw & 1) * 32;
        int n = ntile * 16 + l15;
        int dcol = ds * 32 + quad * 8;
        const float4* wp = (const float4*)(ln0w + n * 256 + dcol);
        const float4* bp = (const float4*)(ln0b + n * 256 + dcol);
        float4 w0 = wp[0], w1 = wp[1];
        float4 c0 = bp[0], c1 = bp[1];
        #pragma unroll 4
        for (int bi = 0; bi < 32; bi++) {
            int b = b0 + bi;
            float mean = sums[b] * (1.f / 1048576.f);
            float rstd = rsqrtf(sums[64 + b] * (1.f / 1048576.f) - mean * mean + LN_EPS);
            const float4* xp = (const float4*)(inp + (size_t)b * 1048576 + n * 256 + dcol);
            float4 v0 = xp[0], v1 = xp[1];
            ushort o[8];
            o[0] = f2bf((v0.x - mean) * rstd * w0.x + c0.x);
            o[1] = f2bf((v0.y - mean) * rstd * w0.y + c0.y);
            o[2] = f2bf((v0.z - mean) * rstd * w0.z + c0.z);
            o[3] = f2bf((v0.w - mean) * rstd * w0.w + c0.w);
            o[4] = f2bf((v1.x - mean) * rstd * w1.x + c1.x);
            o[5] = f2bf((v1.y - mean) * rstd * w1.y + c1.y);
            o[6] = f2bf((v1.z - mean) * rstd * w1.z + c1.z);
            o[7] = f2bf((v1.w - mean) * rstd * w1.w + c1.w);
            *(short8*)(xgs + ((size_t)((b * 256 + ntile) * 8 + ds) * 64 + lane) * 8) = *(short8*)o;
        }
        return;
    }
    // ---- initial q-gen (was kqm); slots0 computed inline ----
    int b = blockIdx.x - 256;
    int g = t >> 8, c = t & 255;
    float muv = mu[c];
    float sgv = __expf(logsig[c]);
    float vals[4]; float s = 0.f, sq = 0.f;
    #pragma unroll
    for (int kk = 0; kk < 4; kk++) {
        float v = muv + sgv * slots_init[b * 4096 + (g * 4 + kk) * 256 + c];
        vals[kk] = v; s += v; sq += v * v;
    }
    #pragma unroll
    for (int m = 1; m < 64; m <<= 1) { s += __shfl_xor(s, m); sq += __shfl_xor(sq, m); }
    if (lane == 0) { wr1[w] = s; wr2[w] = sq; }
    __syncthreads();
    float ts = 0.f, tsq = 0.f;
    #pragma unroll
    for (int i = 0; i < 16; i++) { ts += wr1[i]; tsq += wr2[i]; }
    float m_  = ts * (1.f / 4096.f);
    float rs_ = rsqrtf(tsq * (1.f / 4096.f) - m_ * m_ + LN_EPS);
    #pragma unroll
    for (int kk = 0; kk < 4; kk++) {
        int k = g * 4 + kk;
        slbq[k * 264 + c] = f2bf((vals[kk] - m_) * rs_ * ln1w[k * 256 + c] + ln1b[k * 256 + c]);
    }
    __syncthreads();
    qgen_core(b, t, lane, w, l15, quad, slbq, qsf, qsb, qkl,
              qWc, qb, kWT, kb, qkf, qkb, denom);
}

// ---------------- THE hot kernel (unchanged from R9) ---------------------------------
__launch_bounds__(256, 4)
__global__ void katt(const ushort* __restrict__ xgs, const ushort* __restrict__ qkf,
                     const float* __restrict__ qkb, float* __restrict__ denom,
                     float* __restrict__ partials) {
    int b = blockIdx.x >> 4, chunk = blockIdx.x & 15;
    int tid = threadIdx.x;
    int lane = tid & 63, w = tid >> 6;
    int l15 = lane & 15, quad = lane >> 4;

    __shared__ ushort xtT[16384];       // x^T in ax-B-frag order (32 KB)
    __shared__ ushort attn[16 * 72];    // attn [s][n_local], pitch 72

    short8 ilo, ihi;
    #pragma unroll
    for (int j = 0; j < 8; j++) {
        ilo[j] = (short)((quad * 8 + j == l15)      ? 0x3F80 : 0);
        ihi[j] = (short)((quad * 8 + j == l15 + 16) ? 0x3F80 : 0);
    }
    int wbase = (w >> 1) * 512 + ((w * 2 + (quad >> 1)) & 3) * 128 + l15 * 8 + (quad & 1) * 4;

    short8 qkfr[8];
    #pragma unroll
    for (int ds = 0; ds < 8; ds++)
        qkfr[ds] = *(const short8*)(qkf + ((size_t)(b * 8 + ds) * 512 + lane * 8));
    float4 qo = *(const float4*)(qkb + b * 16 + quad * 4);

    f32x4 pacc[4];
    #pragma unroll
    for (int u = 0; u < 4; u++) pacc[u] = f32x4{0.f, 0.f, 0.f, 0.f};
    float dp0 = 0.f, dp1 = 0.f, dp2 = 0.f, dp3 = 0.f;

    int tile0 = b * 256 + chunk * 16;

    short8 pf[8];
    #pragma unroll
    for (int i = 0; i < 8; i++)
        pf[i] = *(const short8*)(xgs + (((size_t)(tile0 + w) * 8 + i) * 64 + lane) * 8);

    #pragma unroll 1
    for (int sub = 0; sub < 4; sub++) {
        __syncthreads();
        f32x4 dc = f32x4{0.f, 0.f, 0.f, 0.f};
        #pragma unroll
        for (int ds = 0; ds < 8; ds++)
            dc = __builtin_amdgcn_mfma_f32_16x16x32_bf16(qkfr[ds], pf[ds], dc, 0, 0, 0);
        dc[0] += qo.x; dc[1] += qo.y; dc[2] += qo.z; dc[3] += qo.w;
        float mx = fmaxf(fmaxf(dc[0], dc[1]), fmaxf(dc[2], dc[3]));
        mx = fmaxf(mx, __shfl_xor(mx, 16));
        mx = fmaxf(mx, __shfl_xor(mx, 32));
        float e0 = __expf(dc[0] - mx), e1 = __expf(dc[1] - mx);
        float e2 = __expf(dc[2] - mx), e3 = __expf(dc[3] - mx);
        float lsum = e0 + e1 + e2 + e3;
        lsum += __shfl_xor(lsum, 16); lsum += __shfl_xor(lsum, 32);
        float inv = 1.f / lsum;
        float p0 = e0 * inv, p1 = e1 * inv, p2 = e2 * inv, p3 = e3 * inv;
        dp0 += p0; dp1 += p1; dp2 += p2; dp3 += p3;
        attn[(quad * 4 + 0) * 72 + w * 16 + l15] = f2bf(p0);
        attn[(quad * 4 + 1) * 72 + w * 16 + l15] = f2bf(p1);
        attn[(quad * 4 + 2) * 72 + w * 16 + l15] = f2bf(p2);
        attn[(quad * 4 + 3) * 72 + w * 16 + l15] = f2bf(p3);
        f32x4 zz = f32x4{0.f, 0.f, 0.f, 0.f};
        #pragma unroll
        for (int ds = 0; ds < 8; ds++) {
            f32x4 tlo = __builtin_amdgcn_mfma_f32_16x16x32_bf16(pf[ds], ilo, zz, 0, 0, 0);
            f32x4 thi = __builtin_amdgcn_mfma_f32_16x16x32_bf16(pf[ds], ihi, zz, 0, 0, 0);
            unsigned lo0 = (__float_as_uint(tlo[0]) >> 16) | (__float_as_uint(tlo[1]) & 0xFFFF0000u);
            unsigned lo1 = (__float_as_uint(tlo[2]) >> 16) | (__float_as_uint(tlo[3]) & 0xFFFF0000u);
            unsigned hi0 = (__float_as_uint(thi[0]) >> 16) | (__float_as_uint(thi[1]) & 0xFFFF0000u);
            unsigned hi1 = (__float_as_uint(thi[2]) >> 16) | (__float_as_uint(thi[3]) & 0xFFFF0000u);
            *(uint2*)(&xtT[(ds * 2 + 0) * 1024 + wbase]) = make_uint2(lo0, lo1);
            *(uint2*)(&xtT[(ds * 2 + 1) * 1024 + wbase]) = make_uint2(hi0, hi1);
        }
        if (sub < 3) {
            #pragma unroll
            for (int i = 0; i < 8; i++)
                pf[i] = *(const short8*)(xgs + (((size_t)(tile0 + (sub + 1) * 4 + w) * 8 + i) * 64 + lane) * 8);
        }
        __syncthreads();

        #pragma unroll
        for (int ns = 0; ns < 2; ns++) {
            short8 aa = *(const short8*)(&attn[l15 * 72 + ns * 32 + quad * 8]);
            #pragma unroll
            for (int u = 0; u < 4; u++) {
                short8 bb = *(const short8*)(&xtT[((w * 4 + u) * 2 + ns) * 512 + lane * 8]);
                pacc[u] = __builtin_amdgcn_mfma_f32_16x16x32_bf16(aa, bb, pacc[u], 0, 0, 0);
            }
        }
    }

    #pragma unroll
    for (int m = 1; m < 16; m <<= 1) {
        dp0 += __shfl_xor(dp0, m); dp1 += __shfl_xor(dp1, m);
        dp2 += __shfl_xor(dp2, m); dp3 += __shfl_xor(dp3, m);
    }
    if (l15 == 0) {
        atomicAdd(&denom[b * 16 + quad * 4 + 0], dp0);
        atomicAdd(&denom[b * 16 + quad * 4 + 1], dp1);
        atomicAdd(&denom[b * 16 + quad * 4 + 2], dp2);
        atomicAdd(&denom[b * 16 + quad * 4 + 3], dp3);
    }

    float* pout = partials + (size_t)(b * 16 + chunk) * 4096;   // [s][d]
    #pragma unroll
    for (int u = 0; u < 4; u++)
        #pragma unroll
        for (int r = 0; r < 4; r++)
            pout[(quad * 4 + r) * 256 + (w * 4 + u) * 16 + l15] = pacc[u][r];
}

// ---------------- fused tail (unchanged from R9), 1024 threads / 16 waves ------------
__global__ void ktail(const float* __restrict__ partials, const float* __restrict__ denom,
                      const ushort* __restrict__ vWc, const float* __restrict__ vb,
                      const float* __restrict__ ln2w, const float* __restrict__ ln2b,
                      const ushort* __restrict__ m1Wc, const float* __restrict__ m1b,
                      const ushort* __restrict__ m2Wc, const float* __restrict__ m2b,
                      float* __restrict__ final_out, int write_final,
                      const float* __restrict__ ln1w, const float* __restrict__ ln1b,
                      const ushort* __restrict__ qWc_n, const float* __restrict__ qb_n,
                      const ushort* __restrict__ kWT_n, const float* __restrict__ kb_n,
                      ushort* __restrict__ qkf, float* __restrict__ qkb,
                      float* __restrict__ denom_out, int gen) {
    int b = blockIdx.x, t = threadIdx.x;
    int lane = t & 63, w = t >> 6, l15 = lane & 15, quad = lane >> 4;

    __shared__ char pool[60416];
    __shared__ float dnb[16];
    __shared__ float wr1[16], wr2[16];
    ushort* axsb = (ushort*)pool;                  // [0,8448)      P1-2: ax bf16 [16][264]
    ushort* s2b  = (ushort*)(pool + 8448);         // [8448,16896)  P2-4: LN2'd slots bf16
    float*  slt  = (float*)(pool + 16896);         // [16896,33280) P2-5: v-apply out f32 [16][256]
    ushort* hlb  = (ushort*)(pool + 35328);        // [35328,51968) P4-5: relu(h) bf16 [16][520]
    // P6 aliases (regions dead by then):
    float*  slt2 = (float*)pool;                   // [0,16384)     new slots f32
    ushort* slbq = (ushort*)(pool + 16896);        // [16896,25344) LN1'd slots bf16
    ushort* qkl  = (ushort*)(pool + 16896);        // reuse after slbq A-frags loaded
    float*  qsf  = (float*)(pool + 35328);         // [35328,51968) q' f32 [16][260]
    ushort* qsb  = (ushort*)(pool + 51968);        // [51968,60416) q' bf16 [16][264]

    // ---- P1: reduce partials chunks -> axsb ----
    const float* pp = partials + (size_t)b * 65536;
    #pragma unroll
    for (int i = 0; i < 4; i++) {
        int idx = i * 1024 + t;                 // s = idx>>8, d = idx&255
        float ss = 0.f;
        #pragma unroll
        for (int c = 0; c < 16; c++) ss += pp[c * 4096 + idx];
        axsb[(idx >> 8) * 264 + (idx & 255)] = f2bf(ss);
    }
    if (t < 16) dnb[t] = denom[b * 16 + t];
    __syncthreads();

    // ---- P2: v-apply (MFMA); wave w -> e-tile w. slots_mid + LN2 stats ----
    float myv[4];
    {
        short8 af[8];
        #pragma unroll
        for (int ds = 0; ds < 8; ds++)
            af[ds] = *(const short8*)(&axsb[l15 * 264 + ds * 32 + quad * 8]);
        int et = w;
        f32x4 c = f32x4{0.f, 0.f, 0.f, 0.f};
        #pragma unroll
        for (int ds = 0; ds < 8; ds++) {
            short8 bf_ = *(const short8*)(vWc + (size_t)(et * 16 + l15) * 256 + ds * 32 + quad * 8);
            c = __builtin_amdgcn_mfma_f32_16x16x32_bf16(af[ds], bf_, c, 0, 0, 0);
        }
        float vbe = vb[et * 16 + l15];
        #pragma unroll
        for (int r = 0; r < 4; r++) {
            float A = dnb[quad * 4 + r];
            float val = (c[r] + vbe * A) / (A + 1e-7f);
            slt[(quad * 4 + r) * 256 + et * 16 + l15] = val;
            myv[r] = val;
        }
    }
    {
        float s = myv[0] + myv[1] + myv[2] + myv[3];
        float sq = myv[0]*myv[0] + myv[1]*myv[1] + myv[2]*myv[2] + myv[3]*myv[3];
        #pragma unroll
        for (int m = 1; m < 64; m <<= 1) { s += __shfl_xor(s, m); sq += __shfl_xor(sq, m); }
        if (lane == 0) { wr1[w] = s; wr2[w] = sq; }
        __syncthreads();
    }
    float ts = 0.f, tsq = 0.f;
    #pragma unroll
    for (int i = 0; i < 16; i++) { ts += wr1[i]; tsq += wr2[i]; }
    float m2_ = ts * (1.f / 4096.f);
    float rs2 = rsqrtf(tsq * (1.f / 4096.f) - m2_ * m2_ + LN_EPS);
    {
        int e = w * 16 + l15;
        #pragma unroll
        for (int r = 0; r < 4; r++) {
            int ss_ = quad * 4 + r;
            s2b[ss_ * 264 + e] = f2bf((myv[r] - m2_) * rs2 * ln2w[ss_ * 256 + e] + ln2b[ss_ * 256 + e]);
        }
    }
    __syncthreads();

    // ---- P4: MLP1 (MFMA); wave w -> j-tiles {w, w+16} ----
    {
        short8 a2[8];
        #pragma unroll
        for (int ds = 0; ds < 8; ds++)
            a2[ds] = *(const short8*)(&s2b[l15 * 264 + ds * 32 + quad * 8]);
        #pragma unroll
        for (int p = 0; p < 2; p++) {
            int jt = w + p * 16;
            f32x4 c = f32x4{0.f, 0.f, 0.f, 0.f};
            #pragma unroll
            for (int ds = 0; ds < 8; ds++) {
                short8 bf_ = *(const short8*)(m1Wc + (size_t)(jt * 16 + l15) * 256 + ds * 32 + quad * 8);
                c = __builtin_amdgcn_mfma_f32_16x16x32_bf16(a2[ds], bf_, c, 0, 0, 0);
            }
            float bias = m1b[jt * 16 + l15];
            #pragma unroll
            for (int r = 0; r < 4; r++)
                hlb[(quad * 4 + r) * 520 + jt * 16 + l15] = f2bf(fmaxf(c[r] + bias, 0.f));
        }
    }
    __syncthreads();

    // ---- P5: MLP2 (MFMA) + residual; wave w -> d-tile w ----
    {
        short8 a3[16];
        #pragma unroll
        for (int js = 0; js < 16; js++)
            a3[js] = *(const short8*)(&hlb[l15 * 520 + js * 32 + quad * 8]);
        int dt = w;
        f32x4 c = f32x4{0.f, 0.f, 0.f, 0.f};
        #pragma unroll
        for (int js = 0; js < 16; js++) {
            short8 bf_ = *(const short8*)(m2Wc + (size_t)(dt * 16 + l15) * 512 + js * 32 + quad * 8);
            c = __builtin_amdgcn_mfma_f32_16x16x32_bf16(a3[js], bf_, c, 0, 0, 0);
        }
        float b2 = m2b[dt * 16 + l15];
        #pragma unroll
        for (int r = 0; r < 4; r++) {
            int ss_ = quad * 4 + r, d = dt * 16 + l15;
            float val = slt[ss_ * 256 + d] + c[r] + b2;
            slt2[ss_ * 256 + d] = val;
            if (write_final) final_out[(size_t)b * 4096 + ss_ * 256 + d] = val;
        }
    }
    __syncthreads();

    // ---- P6: next-iter q-gen (slots from LDS) ----
    if (gen) {
        int g = t >> 8, cc = t & 255;
        float vals[4]; float s = 0.f, sq = 0.f;
        #pragma unroll
        for (int kk = 0; kk < 4; kk++) {
            float v = slt2[(g * 4 + kk) * 256 + cc];
            vals[kk] = v; s += v; sq += v * v;
        }
        #pragma unroll
        for (int m = 1; m < 64; m <<= 1) { s += __shfl_xor(s, m); sq += __shfl_xor(sq, m); }
        if (lane == 0) { wr1[w] = s; wr2[w] = sq; }
        __syncthreads();
        float ts1 = 0.f, tsq1 = 0.f;
        #pragma unroll
        for (int i = 0; i < 16; i++) { ts1 += wr1[i]; tsq1 += wr2[i]; }
        float m1_ = ts1 * (1.f / 4096.f);
        float rs1 = rsqrtf(tsq1 * (1.f / 4096.f) - m1_ * m1_ + LN_EPS);
        #pragma unroll
        for (int kk = 0; kk < 4; kk++) {
            int k = g * 4 + kk;
            slbq[k * 264 + cc] = f2bf((vals[kk] - m1_) * rs1 * ln1w[k * 256 + cc] + ln1b[k * 256 + cc]);
        }
        __syncthreads();
        qgen_core(b, t, lane, w, l15, quad, slbq, qsf, qsb, qkl,
                  qWc_n, qb_n, kWT_n, kb_n, qkf, qkb, denom_out);
    }
}

extern "C" void kernel_launch(void* const* d_in, const int* in_sizes, int n_in,
                              void* d_out, int out_size, void* d_ws, size_t ws_size,
                              hipStream_t stream) {
    const float* inputs     = (const float*)d_in[0];
    const float* slots_init = (const float*)d_in[1];
    const float* mu         = (const float*)d_in[2];
    const float* logsig     = (const float*)d_in[3];
    const float* ln0w       = (const float*)d_in[4];
    const float* ln0b       = (const float*)d_in[5];
    const float* ln1w       = (const float*)d_in[6];
    const float* ln1b       = (const float*)d_in[7];
    const float* ln2w       = (const float*)d_in[8];
    const float* ln2b       = (const float*)d_in[9];
    const float* qW         = (const float*)d_in[10];
    const float* qb         = (const float*)d_in[11];
    const float* kW         = (const float*)d_in[12];
    const float* kb         = (const float*)d_in[13];
    const float* vW         = (const float*)d_in[14];
    const float* vb         = (const float*)d_in[15];
    const float* m1W        = (const float*)d_in[16];
    const float* m1b        = (const float*)d_in[17];
    const float* m2W        = (const float*)d_in[18];
    const float* m2b        = (const float*)d_in[19];

    char* ws = (char*)d_ws;
    ushort* xgs     = (ushort*)(ws);                   // 134,217,728 B
    float*  partials= (float*)(ws + 134217728);        //  16,777,216 B
    ushort* qkf     = (ushort*)(ws + 150994944);       //     524,288 B
    ushort* qWc     = (ushort*)(ws + 153616384);       //     393,216 B
    ushort* m1Wc    = (ushort*)(ws + 154009600);       //     786,432 B
    ushort* m2Wc    = (ushort*)(ws + 154796032);       //     786,432 B
    ushort* vWc     = (ushort*)(ws + 155582464);       //     393,216 B
    float*  denom   = (float*)(ws + 155975680);        //       4,096 B
    float*  qkb     = (float*)(ws + 155979776);        //       4,096 B
    float*  sums    = (float*)(ws + 155983872);        //         512 B (pad to 155,984,384)
    ushort* kWT     = (ushort*)(ws + 155984384);       //     393,216 B
    // total 156,377,600 B <= 157,295,104 B proven available

    hipMemsetAsync(sums, 0, 512, stream);
    kprep<<<2384, 256, 0, stream>>>(qW, kW, m1W, m2W, vW, qWc, kWT, m1Wc, m2Wc, vWc,
                                    inputs, sums);
    lkq<<<320, 1024, 0, stream>>>(inputs, ln0w, ln0b, sums, xgs,
                                  slots_init, mu, logsig, ln1w, ln1b,
                                  qWc, qb, kWT, kb, qkf, qkb, denom);

    for (int it = 0; it < 3; it++) {
        katt<<<1024, 256, 0, stream>>>(xgs, qkf, qkb, denom, partials);
        int nx = (it < 2) ? it + 1 : 2;
        ktail<<<64, 1024, 0, stream>>>(partials, denom,
                                       vWc + it * 65536, vb + it * 256, ln2w, ln2b,
                                       m1Wc + it * 131072, m1b + it * 512,
                                       m2Wc + it * 131072, m2b + it * 256,
                                       (float*)d_out, it == 2 ? 1 : 0,
                                       ln1w, ln1b,
                                       qWc + nx * 65536, qb + nx * 256,
                                       kWT + nx * 65536, kb + nx * 256,
                                       qkf, qkb, denom, it < 2 ? 1 : 0);
    }
}